// Round 1
// baseline (945.726 us; speedup 1.0000x reference)
//
#include <hip/hip_runtime.h>
#include <cstdint>
#include <cstddef>

#define N_TOK 8192
#define DM 1024
#define DFF 4096
#define NE 8

typedef __attribute__((ext_vector_type(8))) short bf16x8;
typedef __attribute__((ext_vector_type(4))) float f32x4;

__device__ __forceinline__ unsigned short f2bf(float f) {
  union { float f; unsigned u; } v; v.f = f;
  unsigned r = v.u + 0x7FFFu + ((v.u >> 16) & 1u);
  return (unsigned short)(r >> 16);
}

__device__ __forceinline__ void async16(unsigned short* l, const unsigned short* g) {
  __builtin_amdgcn_global_load_lds(
      (const __attribute__((address_space(1))) unsigned int*)g,
      (__attribute__((address_space(3))) unsigned int*)l, 16, 0, 0);
}

// ---------------- init: zero small counters ----------------
__global__ void init_kernel(unsigned* counts, float* Psum) {
  int i = threadIdx.x;
  if (i < NE) { counts[i] = 0u; Psum[i] = 0.f; }
}

// ---------------- transpose + fp32->bf16 convert ----------------
// per expert z: in (R x C) fp32 -> out (C x R) bf16
__global__ __launch_bounds__(256) void transpose_cvt(
    const float* __restrict__ in, unsigned short* __restrict__ out, int R, int C) {
  __shared__ float tile[64][65];
  const float* I = in + (size_t)blockIdx.z * R * C;
  unsigned short* O = out + (size_t)blockIdx.z * R * C;
  const int r0 = blockIdx.y * 64, c0 = blockIdx.x * 64;
  const int c = threadIdx.x & 63, r4 = threadIdx.x >> 6;
#pragma unroll
  for (int i = 0; i < 16; ++i) {
    int r = r4 * 16 + i;
    tile[r][c] = I[(size_t)(r0 + r) * C + c0 + c];
  }
  __syncthreads();
#pragma unroll
  for (int i = 0; i < 16; ++i) {
    int r = r4 * 16 + i;
    O[(size_t)(c0 + r) * R + r0 + c] = f2bf(tile[c][r]);
  }
}

// ---------------- router: logits, softmax, top-2, counts, Psum ----------------
__global__ __launch_bounds__(256) void router_kernel(
    const float* __restrict__ x, const float* __restrict__ Wr,
    unsigned* __restrict__ counts, float* __restrict__ Psum,
    int* __restrict__ tok_e, float* __restrict__ tok_g, int* __restrict__ tok_ls) {
  __shared__ float ps[NE];
  const int tid = threadIdx.x;
  if (tid < NE) ps[tid] = 0.f;
  __syncthreads();
  const int lane = tid & 63, wid = tid >> 6;
  for (int u = 0; u < 4; ++u) {
    const int t = blockIdx.x * 16 + wid * 4 + u;
    float a[NE];
#pragma unroll
    for (int e = 0; e < NE; ++e) a[e] = 0.f;
#pragma unroll
    for (int i = 0; i < 16; ++i) {
      const int d = i * 64 + lane;
      const float xv = x[(size_t)t * DM + d];
      const float* wr = &Wr[(size_t)d * NE];
#pragma unroll
      for (int e = 0; e < NE; ++e) a[e] = fmaf(xv, wr[e], a[e]);
    }
#pragma unroll
    for (int e = 0; e < NE; ++e)
      for (int s = 32; s > 0; s >>= 1) a[e] += __shfl_xor(a[e], s);
    // all lanes redundantly compute softmax + top2
    float mx = a[0];
#pragma unroll
    for (int e = 1; e < NE; ++e) mx = fmaxf(mx, a[e]);
    float p[NE], s = 0.f;
#pragma unroll
    for (int e = 0; e < NE; ++e) { p[e] = expf(a[e] - mx); s += p[e]; }
    float q[NE];
#pragma unroll
    for (int e = 0; e < NE; ++e) q[e] = p[e] / s;
    int i0 = 0; float b0 = q[0];
#pragma unroll
    for (int e = 1; e < NE; ++e) if (q[e] > b0) { b0 = q[e]; i0 = e; }
    int i1 = -1; float b1v = -1.f;
#pragma unroll
    for (int e = 0; e < NE; ++e) if (e != i0 && q[e] > b1v) { b1v = q[e]; i1 = e; }
    const float gs = q[i0] + q[i1];
    const float g0 = q[i0] / gs, g1 = q[i1] / gs;
    if (lane == 0) {
#pragma unroll
      for (int e = 0; e < NE; ++e) atomicAdd(&ps[e], q[e]);
      const int ls0 = (int)atomicAdd(&counts[i0], 1u);
      const int ls1 = (int)atomicAdd(&counts[i1], 1u);
      tok_e[2 * t] = i0; tok_e[2 * t + 1] = i1;
      tok_g[2 * t] = g0; tok_g[2 * t + 1] = g1;
      tok_ls[2 * t] = ls0; tok_ls[2 * t + 1] = ls1;
    }
  }
  __syncthreads();
  if (tid < NE) atomicAdd(&Psum[tid], ps[tid]);
}

// ---------------- offsets (padded prefix) + aux loss ----------------
__global__ void offsets_kernel(const unsigned* __restrict__ counts,
                               const float* __restrict__ Psum,
                               int* __restrict__ offs, float* __restrict__ aux_out) {
  if (threadIdx.x == 0 && blockIdx.x == 0) {
    int o = 0; float aux = 0.f;
    for (int e = 0; e < NE; ++e) {
      offs[e] = o;
      o += (int)((counts[e] + 127u) / 128u) * 128;
      aux += ((float)counts[e] / (float)N_TOK) * (Psum[e] / (float)N_TOK);
    }
    aux_out[0] = 0.01f * (float)NE * aux;
  }
}

// ---------------- gather: x rows -> bf16 slots ----------------
__global__ __launch_bounds__(256) void gather_kernel(
    const float* __restrict__ x, const int* __restrict__ tok_e,
    const int* __restrict__ tok_ls, const int* __restrict__ offs,
    int* __restrict__ tok_slot, unsigned short* __restrict__ Xg) {
  const int t = blockIdx.x;
  __shared__ int ss[2];
  if (threadIdx.x < 2) {
    const int k = threadIdx.x;
    const int e = tok_e[2 * t + k];
    const int sl = offs[e] + tok_ls[2 * t + k];
    ss[k] = sl;
    tok_slot[2 * t + k] = sl;
  }
  __syncthreads();
  const int i = threadIdx.x;
  const float4 v = ((const float4*)x)[(size_t)t * 256 + i];
  ushort4 h;
  h.x = f2bf(v.x); h.y = f2bf(v.y); h.z = f2bf(v.z); h.w = f2bf(v.w);
  ((ushort4*)Xg)[(size_t)ss[0] * 256 + i] = h;
  ((ushort4*)Xg)[(size_t)ss[1] * 256 + i] = h;
}

// ---------------- GEMM: C(rows x Nn) = A(rows x K) * Bt(Nn x K)^T + bias ----------------
template <bool GELU, typename CT>
__global__ __launch_bounds__(256) void gemm_bt(
    const unsigned short* __restrict__ Ag, const unsigned short* __restrict__ Bt,
    const float* __restrict__ bias, CT* __restrict__ Cout,
    const int* __restrict__ offs, const unsigned* __restrict__ counts,
    const int K, const int Nn) {
  const int e = blockIdx.z;
  const unsigned cnt = counts[e];
  const int tm = blockIdx.y;
  if ((unsigned)(tm * 128) >= cnt) return;
  const int tn = blockIdx.x;
  const int row0 = offs[e] + tm * 128;

  const unsigned short* A = Ag + (size_t)row0 * K;
  const unsigned short* B = Bt + ((size_t)e * Nn + (size_t)tn * 128) * K;

  __shared__ __align__(16) unsigned short As[128 * 64];
  __shared__ __align__(16) unsigned short Bs[128 * 64];

  const int tid = threadIdx.x;
  const int lane = tid & 63;
  const int wid = tid >> 6;
  const int wm = wid >> 1, wn = wid & 1;

  f32x4 acc[4][4];
#pragma unroll
  for (int m = 0; m < 4; ++m)
#pragma unroll
    for (int n = 0; n < 4; ++n) acc[m][n] = (f32x4){0.f, 0.f, 0.f, 0.f};

  const int arow = lane & 15;
  const int kof = (lane >> 4) * 8;

  for (int kt = 0; kt < K; kt += 64) {
    __syncthreads();
#pragma unroll
    for (int it = 0; it < 4; ++it) {
      const int cg = it * 4 + wid;       // chunk group 0..15 (wave-uniform)
      const int c = cg * 64 + lane;      // 16B chunk 0..1023
      const int r = c >> 3;              // tile row
      const int co = (c & 7) * 8;        // short offset in row
      async16(&As[cg * 512], A + (size_t)r * K + kt + co);
      async16(&Bs[cg * 512], B + (size_t)r * K + kt + co);
    }
    __syncthreads();
#pragma unroll
    for (int kk = 0; kk < 64; kk += 32) {
      bf16x8 af[4], bfr[4];
#pragma unroll
      for (int m = 0; m < 4; ++m)
        af[m] = *(const bf16x8*)&As[(wm * 64 + m * 16 + arow) * 64 + kk + kof];
#pragma unroll
      for (int n = 0; n < 4; ++n)
        bfr[n] = *(const bf16x8*)&Bs[(wn * 64 + n * 16 + arow) * 64 + kk + kof];
#pragma unroll
      for (int m = 0; m < 4; ++m)
#pragma unroll
        for (int n = 0; n < 4; ++n)
          acc[m][n] = __builtin_amdgcn_mfma_f32_16x16x32_bf16(af[m], bfr[n], acc[m][n], 0, 0, 0);
    }
  }

  const int rl = (lane >> 4) * 4;
  const int cl = lane & 15;
#pragma unroll
  for (int n = 0; n < 4; ++n) {
    const int col = tn * 128 + wn * 64 + n * 16 + cl;
    const float bv = bias[(size_t)e * Nn + col];
#pragma unroll
    for (int m = 0; m < 4; ++m) {
      const int row = row0 + wm * 64 + m * 16 + rl;
#pragma unroll
      for (int j = 0; j < 4; ++j) {
        float v = acc[m][n][j] + bv;
        if (GELU) v = 0.5f * v * (1.f + erff(v * 0.70710678118654752f));
        CT* p = Cout + (size_t)(row + j) * Nn + col;
        if constexpr (sizeof(CT) == 2) { *p = (CT)f2bf(v); } else { *p = (CT)v; }
      }
    }
  }
}

// ---------------- combine: out[t] = g0*Y[s0] + g1*Y[s1] ----------------
__global__ __launch_bounds__(256) void combine_kernel(
    const float* __restrict__ Y, const int* __restrict__ tok_slot,
    const float* __restrict__ tok_g, float* __restrict__ out) {
  const int t = blockIdx.x;
  const int i = threadIdx.x;
  const int s0 = tok_slot[2 * t], s1 = tok_slot[2 * t + 1];
  const float g0 = tok_g[2 * t], g1 = tok_g[2 * t + 1];
  const float4 y0 = ((const float4*)Y)[(size_t)s0 * 256 + i];
  const float4 y1 = ((const float4*)Y)[(size_t)s1 * 256 + i];
  float4 r;
  r.x = g0 * y0.x + g1 * y1.x;
  r.y = g0 * y0.y + g1 * y1.y;
  r.z = g0 * y0.z + g1 * y1.z;
  r.w = g0 * y0.w + g1 * y1.w;
  ((float4*)out)[(size_t)t * 256 + i] = r;
}

extern "C" void kernel_launch(void* const* d_in, const int* in_sizes, int n_in,
                              void* d_out, int out_size, void* d_ws, size_t ws_size,
                              hipStream_t stream) {
  const float* x = (const float*)d_in[0];   // (N, 1024)
  const float* Wr = (const float*)d_in[1];  // (1024, 8)
  const float* W1 = (const float*)d_in[2];  // (8, 1024, 4096)
  const float* b1 = (const float*)d_in[3];  // (8, 4096)
  const float* W2 = (const float*)d_in[4];  // (8, 4096, 1024)
  const float* b2 = (const float*)d_in[5];  // (8, 1024)
  float* out = (float*)d_out;               // N*1024 + 1 (aux)

  const int CAP = 17408;  // 16384 + 8*128 padding headroom

  char* w = (char*)d_ws;
  size_t ob = 0;
  auto take = [&](size_t nbytes) -> void* {
    void* p = w + ob;
    ob = (ob + nbytes + 255) & ~(size_t)255;
    return p;
  };
  unsigned short* W1T = (unsigned short*)take((size_t)NE * DFF * DM * 2);  // (e, f, d) bf16
  unsigned short* W2T = (unsigned short*)take((size_t)NE * DM * DFF * 2);  // (e, d, f) bf16
  unsigned short* Xg = (unsigned short*)take((size_t)CAP * DM * 2);
  unsigned short* H = (unsigned short*)take((size_t)CAP * DFF * 2);
  float* Y = (float*)take((size_t)CAP * DM * 4);
  unsigned* counts = (unsigned*)take(NE * 4);
  float* Psum = (float*)take(NE * 4);
  int* offs = (int*)take(NE * 4);
  int* tok_e = (int*)take(2 * N_TOK * 4);
  float* tok_g = (float*)take(2 * N_TOK * 4);
  int* tok_ls = (int*)take(2 * N_TOK * 4);
  int* tok_slot = (int*)take(2 * N_TOK * 4);
  (void)ws_size; (void)in_sizes; (void)n_in; (void)out_size;

  init_kernel<<<1, 64, 0, stream>>>(counts, Psum);
  router_kernel<<<N_TOK / 16, 256, 0, stream>>>(x, Wr, counts, Psum, tok_e, tok_g, tok_ls);
  // W1 (R=1024, C=4096) -> W1T (4096, 1024)
  transpose_cvt<<<dim3(DFF / 64, DM / 64, NE), 256, 0, stream>>>(W1, W1T, DM, DFF);
  // W2 (R=4096, C=1024) -> W2T (1024, 4096)
  transpose_cvt<<<dim3(DM / 64, DFF / 64, NE), 256, 0, stream>>>(W2, W2T, DFF, DM);
  offsets_kernel<<<1, 64, 0, stream>>>(counts, Psum, offs, out + (size_t)N_TOK * DM);
  gather_kernel<<<N_TOK, 256, 0, stream>>>(x, tok_e, tok_ls, offs, tok_slot, Xg);
  // GEMM1: H = gelu(Xg @ W1 + b1), per expert
  gemm_bt<true, unsigned short><<<dim3(DFF / 128, 64, NE), 256, 0, stream>>>(
      Xg, W1T, b1, H, offs, counts, DM, DFF);
  // GEMM2: Y = H @ W2 + b2, per expert
  gemm_bt<false, float><<<dim3(DM / 128, 64, NE), 256, 0, stream>>>(
      H, W2T, b2, Y, offs, counts, DFF, DM);
  combine_kernel<<<N_TOK, 256, 0, stream>>>(Y, tok_slot, tok_g, out);
}

// Round 2
// 890.613 us; speedup vs baseline: 1.0619x; 1.0619x over previous
//
#include <hip/hip_runtime.h>
#include <cstdint>
#include <cstddef>

#define N_TOK 8192
#define DM 1024
#define DFF 4096
#define NE 8

typedef __attribute__((ext_vector_type(8))) short bf16x8;
typedef __attribute__((ext_vector_type(4))) float f32x4;

__device__ __forceinline__ unsigned short f2bf(float f) {
  union { float f; unsigned u; } v; v.f = f;
  unsigned r = v.u + 0x7FFFu + ((v.u >> 16) & 1u);
  return (unsigned short)(r >> 16);
}

__device__ __forceinline__ void async16(unsigned short* l, const unsigned short* g) {
  __builtin_amdgcn_global_load_lds(
      (const __attribute__((address_space(1))) unsigned int*)g,
      (__attribute__((address_space(3))) unsigned int*)l, 16, 0, 0);
}

// ---------------- init: zero small counters ----------------
__global__ void init_kernel(unsigned* counts, float* Psum) {
  int i = threadIdx.x;
  if (i < NE) { counts[i] = 0u; Psum[i] = 0.f; }
}

// ---------------- transpose + fp32->bf16 convert ----------------
// per expert z: in (R x C) fp32 -> out (C x R) bf16
__global__ __launch_bounds__(256) void transpose_cvt(
    const float* __restrict__ in, unsigned short* __restrict__ out, int R, int C) {
  __shared__ float tile[64][65];
  const float* I = in + (size_t)blockIdx.z * R * C;
  unsigned short* O = out + (size_t)blockIdx.z * R * C;
  const int r0 = blockIdx.y * 64, c0 = blockIdx.x * 64;
  const int c = threadIdx.x & 63, r4 = threadIdx.x >> 6;
#pragma unroll
  for (int i = 0; i < 16; ++i) {
    int r = r4 * 16 + i;
    tile[r][c] = I[(size_t)(r0 + r) * C + c0 + c];
  }
  __syncthreads();
#pragma unroll
  for (int i = 0; i < 16; ++i) {
    int r = r4 * 16 + i;
    O[(size_t)(c0 + r) * R + r0 + c] = f2bf(tile[c][r]);
  }
}

// ---------------- router: logits, softmax, top-2, counts, Psum ----------------
__global__ __launch_bounds__(256) void router_kernel(
    const float* __restrict__ x, const float* __restrict__ Wr,
    unsigned* __restrict__ counts, float* __restrict__ Psum,
    int* __restrict__ tok_e, float* __restrict__ tok_g, int* __restrict__ tok_ls) {
  __shared__ float ps[NE];
  const int tid = threadIdx.x;
  if (tid < NE) ps[tid] = 0.f;
  __syncthreads();
  const int lane = tid & 63, wid = tid >> 6;
  for (int u = 0; u < 4; ++u) {
    const int t = blockIdx.x * 16 + wid * 4 + u;
    float a[NE];
#pragma unroll
    for (int e = 0; e < NE; ++e) a[e] = 0.f;
#pragma unroll
    for (int i = 0; i < 16; ++i) {
      const int d = i * 64 + lane;
      const float xv = x[(size_t)t * DM + d];
      const float* wr = &Wr[(size_t)d * NE];
#pragma unroll
      for (int e = 0; e < NE; ++e) a[e] = fmaf(xv, wr[e], a[e]);
    }
#pragma unroll
    for (int e = 0; e < NE; ++e)
      for (int s = 32; s > 0; s >>= 1) a[e] += __shfl_xor(a[e], s);
    // all lanes redundantly compute softmax + top2
    float mx = a[0];
#pragma unroll
    for (int e = 1; e < NE; ++e) mx = fmaxf(mx, a[e]);
    float p[NE], s = 0.f;
#pragma unroll
    for (int e = 0; e < NE; ++e) { p[e] = expf(a[e] - mx); s += p[e]; }
    float q[NE];
#pragma unroll
    for (int e = 0; e < NE; ++e) q[e] = p[e] / s;
    int i0 = 0; float b0 = q[0];
#pragma unroll
    for (int e = 1; e < NE; ++e) if (q[e] > b0) { b0 = q[e]; i0 = e; }
    int i1 = -1; float b1v = -1.f;
#pragma unroll
    for (int e = 0; e < NE; ++e) if (e != i0 && q[e] > b1v) { b1v = q[e]; i1 = e; }
    const float gs = q[i0] + q[i1];
    const float g0 = q[i0] / gs, g1 = q[i1] / gs;
    if (lane == 0) {
#pragma unroll
      for (int e = 0; e < NE; ++e) atomicAdd(&ps[e], q[e]);
      const int ls0 = (int)atomicAdd(&counts[i0], 1u);
      const int ls1 = (int)atomicAdd(&counts[i1], 1u);
      tok_e[2 * t] = i0; tok_e[2 * t + 1] = i1;
      tok_g[2 * t] = g0; tok_g[2 * t + 1] = g1;
      tok_ls[2 * t] = ls0; tok_ls[2 * t + 1] = ls1;
    }
  }
  __syncthreads();
  if (tid < NE) atomicAdd(&Psum[tid], ps[tid]);
}

// ---------------- offsets (padded prefix) + aux loss ----------------
__global__ void offsets_kernel(const unsigned* __restrict__ counts,
                               const float* __restrict__ Psum,
                               int* __restrict__ offs, float* __restrict__ aux_out) {
  if (threadIdx.x == 0 && blockIdx.x == 0) {
    int o = 0; float aux = 0.f;
    for (int e = 0; e < NE; ++e) {
      offs[e] = o;
      o += (int)((counts[e] + 127u) / 128u) * 128;
      aux += ((float)counts[e] / (float)N_TOK) * (Psum[e] / (float)N_TOK);
    }
    aux_out[0] = 0.01f * (float)NE * aux;
  }
}

// ---------------- gather: x rows -> bf16 slots ----------------
__global__ __launch_bounds__(256) void gather_kernel(
    const float* __restrict__ x, const int* __restrict__ tok_e,
    const int* __restrict__ tok_ls, const int* __restrict__ offs,
    int* __restrict__ tok_slot, unsigned short* __restrict__ Xg) {
  const int t = blockIdx.x;
  __shared__ int ss[2];
  if (threadIdx.x < 2) {
    const int k = threadIdx.x;
    const int e = tok_e[2 * t + k];
    const int sl = offs[e] + tok_ls[2 * t + k];
    ss[k] = sl;
    tok_slot[2 * t + k] = sl;
  }
  __syncthreads();
  const int i = threadIdx.x;
  const float4 v = ((const float4*)x)[(size_t)t * 256 + i];
  ushort4 h;
  h.x = f2bf(v.x); h.y = f2bf(v.y); h.z = f2bf(v.z); h.w = f2bf(v.w);
  ((ushort4*)Xg)[(size_t)ss[0] * 256 + i] = h;
  ((ushort4*)Xg)[(size_t)ss[1] * 256 + i] = h;
}

// ---------------- GEMM: C(rows x Nn) = A(rows x K) * Bt(Nn x K)^T + bias ----------------
// LDS tiles are [128 rows][8 chunks of 16B]; chunk index XOR-swizzled with (row&7)
// (T2). global_load_lds writes linearly, so the swizzle is applied to the per-lane
// GLOBAL source address (inverse==same involution) and to the ds_read address.
template <bool GELU, typename CT>
__global__ __launch_bounds__(256) void gemm_bt(
    const unsigned short* __restrict__ Ag, const unsigned short* __restrict__ Bt,
    const float* __restrict__ bias, CT* __restrict__ Cout,
    const int* __restrict__ offs, const unsigned* __restrict__ counts,
    const int K, const int Nn) {
  const int e = blockIdx.z;
  const unsigned cnt = counts[e];
  const int tm = blockIdx.y;
  if ((unsigned)(tm * 128) >= cnt) return;
  const int tn = blockIdx.x;
  const int row0 = offs[e] + tm * 128;

  const unsigned short* A = Ag + (size_t)row0 * K;
  const unsigned short* B = Bt + ((size_t)e * Nn + (size_t)tn * 128) * K;

  __shared__ __align__(16) unsigned short As[128 * 64];
  __shared__ __align__(16) unsigned short Bs[128 * 64];

  const int tid = threadIdx.x;
  const int lane = tid & 63;
  const int wid = tid >> 6;
  const int wm = wid >> 1, wn = wid & 1;

  f32x4 acc[4][4];
#pragma unroll
  for (int m = 0; m < 4; ++m)
#pragma unroll
    for (int n = 0; n < 4; ++n) acc[m][n] = (f32x4){0.f, 0.f, 0.f, 0.f};

  const int arow = lane & 15;
  const int swz = arow & 7;          // XOR value for this lane's fragment rows
  const int lg = lane >> 4;          // 0..3 lane-group -> chunk offset

  for (int kt = 0; kt < K; kt += 64) {
    __syncthreads();
#pragma unroll
    for (int it = 0; it < 4; ++it) {
      const int cg = it * 4 + wid;       // chunk group 0..15 (wave-uniform)
      const int c = cg * 64 + lane;      // 16B chunk 0..1023
      const int r = c >> 3;              // tile row
      const int k8 = c & 7;              // chunk-in-row
      const int co = (k8 ^ (r & 7)) * 8; // inverse-swizzled source chunk (shorts)
      async16(&As[cg * 512], A + (size_t)r * K + kt + co);
      async16(&Bs[cg * 512], B + (size_t)r * K + kt + co);
    }
    __syncthreads();
#pragma unroll
    for (int kk = 0; kk < 64; kk += 32) {
      const int kc = (kk >> 3) + lg;           // logical chunk 0..7
      const int col = ((kc ^ swz) << 3);       // swizzled short offset in row
      bf16x8 af[4], bfr[4];
#pragma unroll
      for (int m = 0; m < 4; ++m)
        af[m] = *(const bf16x8*)&As[(wm * 64 + m * 16 + arow) * 64 + col];
#pragma unroll
      for (int n = 0; n < 4; ++n)
        bfr[n] = *(const bf16x8*)&Bs[(wn * 64 + n * 16 + arow) * 64 + col];
#pragma unroll
      for (int m = 0; m < 4; ++m)
#pragma unroll
        for (int n = 0; n < 4; ++n)
          acc[m][n] = __builtin_amdgcn_mfma_f32_16x16x32_bf16(af[m], bfr[n], acc[m][n], 0, 0, 0);
    }
  }

  const int rl = (lane >> 4) * 4;
  const int cl = lane & 15;
#pragma unroll
  for (int n = 0; n < 4; ++n) {
    const int col = tn * 128 + wn * 64 + n * 16 + cl;
    const float bv = bias[(size_t)e * Nn + col];
#pragma unroll
    for (int m = 0; m < 4; ++m) {
      const int row = row0 + wm * 64 + m * 16 + rl;
#pragma unroll
      for (int j = 0; j < 4; ++j) {
        float v = acc[m][n][j] + bv;
        if (GELU) v = 0.5f * v * (1.f + erff(v * 0.70710678118654752f));
        CT* p = Cout + (size_t)(row + j) * Nn + col;
        if constexpr (sizeof(CT) == 2) { *p = (CT)f2bf(v); } else { *p = (CT)v; }
      }
    }
  }
}

// ---------------- combine: out[t] = g0*Y[s0] + g1*Y[s1] ----------------
__global__ __launch_bounds__(256) void combine_kernel(
    const float* __restrict__ Y, const int* __restrict__ tok_slot,
    const float* __restrict__ tok_g, float* __restrict__ out) {
  const int t = blockIdx.x;
  const int i = threadIdx.x;
  const int s0 = tok_slot[2 * t], s1 = tok_slot[2 * t + 1];
  const float g0 = tok_g[2 * t], g1 = tok_g[2 * t + 1];
  const float4 y0 = ((const float4*)Y)[(size_t)s0 * 256 + i];
  const float4 y1 = ((const float4*)Y)[(size_t)s1 * 256 + i];
  float4 r;
  r.x = g0 * y0.x + g1 * y1.x;
  r.y = g0 * y0.y + g1 * y1.y;
  r.z = g0 * y0.z + g1 * y1.z;
  r.w = g0 * y0.w + g1 * y1.w;
  ((float4*)out)[(size_t)t * 256 + i] = r;
}

extern "C" void kernel_launch(void* const* d_in, const int* in_sizes, int n_in,
                              void* d_out, int out_size, void* d_ws, size_t ws_size,
                              hipStream_t stream) {
  const float* x = (const float*)d_in[0];   // (N, 1024)
  const float* Wr = (const float*)d_in[1];  // (1024, 8)
  const float* W1 = (const float*)d_in[2];  // (8, 1024, 4096)
  const float* b1 = (const float*)d_in[3];  // (8, 4096)
  const float* W2 = (const float*)d_in[4];  // (8, 4096, 1024)
  const float* b2 = (const float*)d_in[5];  // (8, 1024)
  float* out = (float*)d_out;               // N*1024 + 1 (aux)

  const int CAP = 17408;  // 16384 + 8*128 padding headroom

  char* w = (char*)d_ws;
  size_t ob = 0;
  auto take = [&](size_t nbytes) -> void* {
    void* p = w + ob;
    ob = (ob + nbytes + 255) & ~(size_t)255;
    return p;
  };
  unsigned short* W1T = (unsigned short*)take((size_t)NE * DFF * DM * 2);  // (e, f, d) bf16
  unsigned short* W2T = (unsigned short*)take((size_t)NE * DM * DFF * 2);  // (e, d, f) bf16
  unsigned short* Xg = (unsigned short*)take((size_t)CAP * DM * 2);
  unsigned short* H = (unsigned short*)take((size_t)CAP * DFF * 2);
  float* Y = (float*)take((size_t)CAP * DM * 4);
  unsigned* counts = (unsigned*)take(NE * 4);
  float* Psum = (float*)take(NE * 4);
  int* offs = (int*)take(NE * 4);
  int* tok_e = (int*)take(2 * N_TOK * 4);
  float* tok_g = (float*)take(2 * N_TOK * 4);
  int* tok_ls = (int*)take(2 * N_TOK * 4);
  int* tok_slot = (int*)take(2 * N_TOK * 4);
  (void)ws_size; (void)in_sizes; (void)n_in; (void)out_size;

  init_kernel<<<1, 64, 0, stream>>>(counts, Psum);
  router_kernel<<<N_TOK / 16, 256, 0, stream>>>(x, Wr, counts, Psum, tok_e, tok_g, tok_ls);
  // W1 (R=1024, C=4096) -> W1T (4096, 1024)
  transpose_cvt<<<dim3(DFF / 64, DM / 64, NE), 256, 0, stream>>>(W1, W1T, DM, DFF);
  // W2 (R=4096, C=1024) -> W2T (1024, 4096)
  transpose_cvt<<<dim3(DM / 64, DFF / 64, NE), 256, 0, stream>>>(W2, W2T, DFF, DM);
  offsets_kernel<<<1, 64, 0, stream>>>(counts, Psum, offs, out + (size_t)N_TOK * DM);
  gather_kernel<<<N_TOK, 256, 0, stream>>>(x, tok_e, tok_ls, offs, tok_slot, Xg);
  // GEMM1: H = gelu(Xg @ W1 + b1), per expert
  gemm_bt<true, unsigned short><<<dim3(DFF / 128, 64, NE), 256, 0, stream>>>(
      Xg, W1T, b1, H, offs, counts, DM, DFF);
  // GEMM2: Y = H @ W2 + b2, per expert
  gemm_bt<false, float><<<dim3(DM / 128, 64, NE), 256, 0, stream>>>(
      H, W2T, b2, Y, offs, counts, DFF, DM);
  combine_kernel<<<N_TOK, 256, 0, stream>>>(Y, tok_slot, tok_g, out);
}

// Round 3
// 805.006 us; speedup vs baseline: 1.1748x; 1.1063x over previous
//
#include <hip/hip_runtime.h>
#include <cstdint>
#include <cstddef>

#define N_TOK 8192
#define DM 1024
#define DFF 4096
#define NE 8
#define PAD 256
#define CAP (N_TOK * 2 + NE * PAD)  // 18432

typedef __attribute__((ext_vector_type(8))) short bf16x8;
typedef __attribute__((ext_vector_type(4))) float f32x4;

__device__ __forceinline__ unsigned short f2bf(float f) {
  union { float f; unsigned u; } v; v.f = f;
  unsigned r = v.u + 0x7FFFu + ((v.u >> 16) & 1u);
  return (unsigned short)(r >> 16);
}

__device__ __forceinline__ void async16(unsigned short* l, const unsigned short* g) {
  __builtin_amdgcn_global_load_lds(
      (const __attribute__((address_space(1))) unsigned int*)g,
      (__attribute__((address_space(3))) unsigned int*)l, 16, 0, 0);
}

// ---------------- init ----------------
__global__ void init_kernel(unsigned* counts, float* Psum) {
  int i = threadIdx.x;
  if (i < NE) { counts[i] = 0u; Psum[i] = 0.f; }
}

// ---------------- transpose + fp32->bf16 convert ----------------
__global__ __launch_bounds__(256) void transpose_cvt(
    const float* __restrict__ in, unsigned short* __restrict__ out, int R, int C) {
  __shared__ float tile[64][65];
  const float* I = in + (size_t)blockIdx.z * R * C;
  unsigned short* O = out + (size_t)blockIdx.z * R * C;
  const int r0 = blockIdx.y * 64, c0 = blockIdx.x * 64;
  const int c = threadIdx.x & 63, r4 = threadIdx.x >> 6;
#pragma unroll
  for (int i = 0; i < 16; ++i) {
    int r = r4 * 16 + i;
    tile[r][c] = I[(size_t)(r0 + r) * C + c0 + c];
  }
  __syncthreads();
#pragma unroll
  for (int i = 0; i < 16; ++i) {
    int r = r4 * 16 + i;
    O[(size_t)(c0 + r) * R + r0 + c] = f2bf(tile[c][r]);
  }
}

// ---------------- router ----------------
__global__ __launch_bounds__(256) void router_kernel(
    const float* __restrict__ x, const float* __restrict__ Wr,
    unsigned* __restrict__ counts, float* __restrict__ Psum,
    int* __restrict__ tok_e, float* __restrict__ tok_g, int* __restrict__ tok_ls) {
  __shared__ float ps[NE];
  const int tid = threadIdx.x;
  if (tid < NE) ps[tid] = 0.f;
  __syncthreads();
  const int lane = tid & 63, wid = tid >> 6;
  for (int u = 0; u < 4; ++u) {
    const int t = blockIdx.x * 16 + wid * 4 + u;
    float a[NE];
#pragma unroll
    for (int e = 0; e < NE; ++e) a[e] = 0.f;
#pragma unroll
    for (int i = 0; i < 16; ++i) {
      const int d = i * 64 + lane;
      const float xv = x[(size_t)t * DM + d];
      const float* wr = &Wr[(size_t)d * NE];
#pragma unroll
      for (int e = 0; e < NE; ++e) a[e] = fmaf(xv, wr[e], a[e]);
    }
#pragma unroll
    for (int e = 0; e < NE; ++e)
      for (int s = 32; s > 0; s >>= 1) a[e] += __shfl_xor(a[e], s);
    float mx = a[0];
#pragma unroll
    for (int e = 1; e < NE; ++e) mx = fmaxf(mx, a[e]);
    float p[NE], s = 0.f;
#pragma unroll
    for (int e = 0; e < NE; ++e) { p[e] = expf(a[e] - mx); s += p[e]; }
    float q[NE];
#pragma unroll
    for (int e = 0; e < NE; ++e) q[e] = p[e] / s;
    int i0 = 0; float b0 = q[0];
#pragma unroll
    for (int e = 1; e < NE; ++e) if (q[e] > b0) { b0 = q[e]; i0 = e; }
    int i1 = -1; float b1v = -1.f;
#pragma unroll
    for (int e = 0; e < NE; ++e) if (e != i0 && q[e] > b1v) { b1v = q[e]; i1 = e; }
    const float gs = q[i0] + q[i1];
    const float g0 = q[i0] / gs, g1 = q[i1] / gs;
    if (lane == 0) {
#pragma unroll
      for (int e = 0; e < NE; ++e) atomicAdd(&ps[e], q[e]);
      const int ls0 = (int)atomicAdd(&counts[i0], 1u);
      const int ls1 = (int)atomicAdd(&counts[i1], 1u);
      tok_e[2 * t] = i0; tok_e[2 * t + 1] = i1;
      tok_g[2 * t] = g0; tok_g[2 * t + 1] = g1;
      tok_ls[2 * t] = ls0; tok_ls[2 * t + 1] = ls1;
    }
  }
  __syncthreads();
  if (tid < NE) atomicAdd(&Psum[tid], ps[tid]);
}

// ---------------- offsets (256-padded prefix) + aux loss ----------------
__global__ void offsets_kernel(const unsigned* __restrict__ counts,
                               const float* __restrict__ Psum,
                               int* __restrict__ offs, float* __restrict__ aux_out) {
  if (threadIdx.x == 0 && blockIdx.x == 0) {
    int o = 0; float aux = 0.f;
    for (int e = 0; e < NE; ++e) {
      offs[e] = o;
      o += (int)((counts[e] + (PAD - 1u)) / PAD) * PAD;
      aux += ((float)counts[e] / (float)N_TOK) * (Psum[e] / (float)N_TOK);
    }
    aux_out[0] = 0.01f * (float)NE * aux;
  }
}

// ---------------- gather ----------------
__global__ __launch_bounds__(256) void gather_kernel(
    const float* __restrict__ x, const int* __restrict__ tok_e,
    const int* __restrict__ tok_ls, const int* __restrict__ offs,
    int* __restrict__ tok_slot, unsigned short* __restrict__ Xg) {
  const int t = blockIdx.x;
  __shared__ int ss[2];
  if (threadIdx.x < 2) {
    const int k = threadIdx.x;
    const int e = tok_e[2 * t + k];
    const int sl = offs[e] + tok_ls[2 * t + k];
    ss[k] = sl;
    tok_slot[2 * t + k] = sl;
  }
  __syncthreads();
  const int i = threadIdx.x;
  const float4 v = ((const float4*)x)[(size_t)t * 256 + i];
  ushort4 h;
  h.x = f2bf(v.x); h.y = f2bf(v.y); h.z = f2bf(v.z); h.w = f2bf(v.w);
  ((ushort4*)Xg)[(size_t)ss[0] * 256 + i] = h;
  ((ushort4*)Xg)[(size_t)ss[1] * 256 + i] = h;
}

// ---------------- 8-phase 256x256 GEMM (T2+T3+T4+T5) ----------------
// C(rows x Nn) = A(rows x K) * Bt(Nn x K)^T + bias. 512 thr = 8 waves (2M x 4N).
// LDS (dynamic 128KB): per matrix [2 dbuf][2 k-slice][256 rows][32 cols bf16],
// 16B chunks XOR-swizzled by (row&3), inverse-swizzle on global src (rule #21).
// Half-tile = 256 rows x 32 cols (one k-slice). Stage slots within tile j:
//  p0: A-s1(j+1)  p1: B-s1(j+1)  p2: A-s0(j+2)  p3: B-s0(j+2)
// Each region staged exactly one barrier after its last reader; vmcnt(8)
// (= 4 halves in flight) at odd phases guarantees data 4 slots back has landed.
template <bool GELU, typename CT>
__global__ __launch_bounds__(512, 2) void gemm8(
    const unsigned short* __restrict__ Ag, const unsigned short* __restrict__ Bt,
    const float* __restrict__ bias, CT* __restrict__ Cout,
    const int* __restrict__ offs, const unsigned* __restrict__ counts,
    const int K, const int Nn) {
  const int e = blockIdx.z;
  const unsigned cnt = counts[e];
  const int tm = blockIdx.y;
  if ((unsigned)(tm * 256) >= cnt) return;
  const int tn = blockIdx.x;
  const int row0 = offs[e] + tm * 256;

  const unsigned short* A = Ag + (size_t)row0 * K;
  const unsigned short* B = Bt + ((size_t)e * Nn + (size_t)tn * 256) * K;

  extern __shared__ unsigned short lds[];
  unsigned short* LA = lds;           // 32768 shorts
  unsigned short* LB = lds + 32768;

  const int tid = threadIdx.x;
  const int lane = tid & 63;
  const int wid = tid >> 6;
  const int wm = wid >> 2;   // 0..1
  const int wn = wid & 3;    // 0..3
  const int arow = lane & 15;
  const int kc = lane >> 4;  // 16B chunk within 32-col slice
  const int nt = K >> 6;

  f32x4 acc[8][4];
#pragma unroll
  for (int m = 0; m < 8; ++m)
#pragma unroll
    for (int n = 0; n < 4; ++n) acc[m][n] = (f32x4){0.f, 0.f, 0.f, 0.f};

  auto stage = [&](unsigned short* Lb, const unsigned short* G, int db, int sl, int kt) {
    unsigned short* hb = Lb + ((db * 2 + sl) << 13);
#pragma unroll
    for (int it = 0; it < 2; ++it) {
      const int c = it * 512 + tid;
      const int r = c >> 2;
      const int k4 = c & 3;
      const unsigned short* src = G + (size_t)r * K + kt * 64 + sl * 32 + ((k4 ^ (r & 3)) << 3);
      async16(hb + (size_t)(it * 512 + wid * 64) * 8, src);
    }
  };
  auto ldA = [&](int db, int sl, int mf) -> bf16x8 {
    const int R = wm * 128 + mf * 16 + arow;
    return *(const bf16x8*)&LA[((db * 2 + sl) << 13) + R * 32 + ((kc ^ (R & 3)) << 3)];
  };
  auto ldB = [&](int db, int sl, int nf) -> bf16x8 {
    const int R = wn * 64 + nf * 16 + arow;
    return *(const bf16x8*)&LB[((db * 2 + sl) << 13) + R * 32 + ((kc ^ (R & 3)) << 3)];
  };

  // prologue: T0 all 4 halves + T1 s0 halves (6 halves = 12 loads/wave)
  stage(LA, A, 0, 0, 0);
  stage(LB, B, 0, 0, 0);
  stage(LA, A, 0, 1, 0);
  stage(LB, B, 0, 1, 0);
  stage(LA, A, 1, 0, 1);
  stage(LB, B, 1, 0, 1);
  asm volatile("s_waitcnt vmcnt(8)");
  __builtin_amdgcn_sched_barrier(0);
  __builtin_amdgcn_s_barrier();

  bf16x8 bfr[4];
  for (int j = 0; j < nt; ++j) {
    const int db = j & 1;
    const int dbn = db ^ 1;
    const int j1 = (j + 1 < nt) ? j + 1 : 0;  // clamped src; dest region is dead
    const int j2 = (j + 2 < nt) ? j + 2 : 0;
    bf16x8 afr[4];

    // ---- phase 0: (s0, q0); stage A-s1 of T(j+1)
#pragma unroll
    for (int n = 0; n < 4; ++n) bfr[n] = ldB(db, 0, n);
#pragma unroll
    for (int i = 0; i < 4; ++i) afr[i] = ldA(db, 0, i);
    stage(LA, A, dbn, 1, j1);
    __builtin_amdgcn_sched_barrier(0);
    __builtin_amdgcn_s_barrier();
    asm volatile("s_waitcnt lgkmcnt(0)");
    __builtin_amdgcn_sched_barrier(0);
    __builtin_amdgcn_s_setprio(1);
#pragma unroll
    for (int i = 0; i < 4; ++i)
#pragma unroll
      for (int n = 0; n < 4; ++n)
        acc[i][n] = __builtin_amdgcn_mfma_f32_16x16x32_bf16(afr[i], bfr[n], acc[i][n], 0, 0, 0);
    __builtin_amdgcn_s_setprio(0);
    __builtin_amdgcn_sched_barrier(0);
    __builtin_amdgcn_s_barrier();

    // ---- phase 1: (s0, q1); stage B-s1 of T(j+1); vmcnt
#pragma unroll
    for (int i = 0; i < 4; ++i) afr[i] = ldA(db, 0, 4 + i);
    stage(LB, B, dbn, 1, j1);
    asm volatile("s_waitcnt vmcnt(8)");
    __builtin_amdgcn_sched_barrier(0);
    __builtin_amdgcn_s_barrier();
    asm volatile("s_waitcnt lgkmcnt(0)");
    __builtin_amdgcn_sched_barrier(0);
    __builtin_amdgcn_s_setprio(1);
#pragma unroll
    for (int i = 0; i < 4; ++i)
#pragma unroll
      for (int n = 0; n < 4; ++n)
        acc[4 + i][n] = __builtin_amdgcn_mfma_f32_16x16x32_bf16(afr[i], bfr[n], acc[4 + i][n], 0, 0, 0);
    __builtin_amdgcn_s_setprio(0);
    __builtin_amdgcn_sched_barrier(0);
    __builtin_amdgcn_s_barrier();

    // ---- phase 2: (s1, q0); stage A-s0 of T(j+2)
#pragma unroll
    for (int n = 0; n < 4; ++n) bfr[n] = ldB(db, 1, n);
#pragma unroll
    for (int i = 0; i < 4; ++i) afr[i] = ldA(db, 1, i);
    stage(LA, A, db, 0, j2);
    __builtin_amdgcn_sched_barrier(0);
    __builtin_amdgcn_s_barrier();
    asm volatile("s_waitcnt lgkmcnt(0)");
    __builtin_amdgcn_sched_barrier(0);
    __builtin_amdgcn_s_setprio(1);
#pragma unroll
    for (int i = 0; i < 4; ++i)
#pragma unroll
      for (int n = 0; n < 4; ++n)
        acc[i][n] = __builtin_amdgcn_mfma_f32_16x16x32_bf16(afr[i], bfr[n], acc[i][n], 0, 0, 0);
    __builtin_amdgcn_s_setprio(0);
    __builtin_amdgcn_sched_barrier(0);
    __builtin_amdgcn_s_barrier();

    // ---- phase 3: (s1, q1); stage B-s0 of T(j+2); vmcnt
#pragma unroll
    for (int i = 0; i < 4; ++i) afr[i] = ldA(db, 1, 4 + i);
    stage(LB, B, db, 0, j2);
    asm volatile("s_waitcnt vmcnt(8)");
    __builtin_amdgcn_sched_barrier(0);
    __builtin_amdgcn_s_barrier();
    asm volatile("s_waitcnt lgkmcnt(0)");
    __builtin_amdgcn_sched_barrier(0);
    __builtin_amdgcn_s_setprio(1);
#pragma unroll
    for (int i = 0; i < 4; ++i)
#pragma unroll
      for (int n = 0; n < 4; ++n)
        acc[4 + i][n] = __builtin_amdgcn_mfma_f32_16x16x32_bf16(afr[i], bfr[n], acc[4 + i][n], 0, 0, 0);
    __builtin_amdgcn_s_setprio(0);
    __builtin_amdgcn_sched_barrier(0);
    __builtin_amdgcn_s_barrier();
  }

  // epilogue
  const int rl = (lane >> 4) * 4;
  const int cl = lane & 15;
#pragma unroll
  for (int n = 0; n < 4; ++n) {
    const int col = tn * 256 + wn * 64 + n * 16 + cl;
    const float bv = bias[(size_t)e * Nn + col];
#pragma unroll
    for (int m = 0; m < 8; ++m) {
      const int row = row0 + wm * 128 + m * 16 + rl;
#pragma unroll
      for (int jj = 0; jj < 4; ++jj) {
        float v = acc[m][n][jj] + bv;
        if (GELU) v = 0.5f * v * (1.f + erff(v * 0.70710678118654752f));
        CT* p = Cout + (size_t)(row + jj) * Nn + col;
        if constexpr (sizeof(CT) == 2) { *p = (CT)f2bf(v); } else { *p = (CT)v; }
      }
    }
  }
}

// ---------------- combine ----------------
__global__ __launch_bounds__(256) void combine_kernel(
    const float* __restrict__ Y, const int* __restrict__ tok_slot,
    const float* __restrict__ tok_g, float* __restrict__ out) {
  const int t = blockIdx.x;
  const int i = threadIdx.x;
  const int s0 = tok_slot[2 * t], s1 = tok_slot[2 * t + 1];
  const float g0 = tok_g[2 * t], g1 = tok_g[2 * t + 1];
  const float4 y0 = ((const float4*)Y)[(size_t)s0 * 256 + i];
  const float4 y1 = ((const float4*)Y)[(size_t)s1 * 256 + i];
  float4 r;
  r.x = g0 * y0.x + g1 * y1.x;
  r.y = g0 * y0.y + g1 * y1.y;
  r.z = g0 * y0.z + g1 * y1.z;
  r.w = g0 * y0.w + g1 * y1.w;
  ((float4*)out)[(size_t)t * 256 + i] = r;
}

extern "C" void kernel_launch(void* const* d_in, const int* in_sizes, int n_in,
                              void* d_out, int out_size, void* d_ws, size_t ws_size,
                              hipStream_t stream) {
  const float* x = (const float*)d_in[0];
  const float* Wr = (const float*)d_in[1];
  const float* W1 = (const float*)d_in[2];
  const float* b1 = (const float*)d_in[3];
  const float* W2 = (const float*)d_in[4];
  const float* b2 = (const float*)d_in[5];
  float* out = (float*)d_out;

  char* w = (char*)d_ws;
  size_t ob = 0;
  auto take = [&](size_t nbytes) -> void* {
    void* p = w + ob;
    ob = (ob + nbytes + 255) & ~(size_t)255;
    return p;
  };
  // layout with overlap: Y reuses W1T+Xg region (both dead after GEMM1)
  unsigned short* W2T = (unsigned short*)take((size_t)NE * DM * DFF * 2);   // 64MB
  unsigned short* H = (unsigned short*)take((size_t)CAP * DFF * 2);         // 151MB
  char* R = (char*)take((size_t)NE * DFF * DM * 2 + (size_t)CAP * DM * 2);  // 100MB
  unsigned short* W1T = (unsigned short*)R;
  unsigned short* Xg = (unsigned short*)(R + (size_t)NE * DFF * DM * 2);
  float* Y = (float*)R;  // 72MB, overlaps dead W1T (64MB) + head of Xg
  unsigned* counts = (unsigned*)take(NE * 4);
  float* Psum = (float*)take(NE * 4);
  int* offs = (int*)take(NE * 4);
  int* tok_e = (int*)take(2 * N_TOK * 4);
  float* tok_g = (float*)take(2 * N_TOK * 4);
  int* tok_ls = (int*)take(2 * N_TOK * 4);
  int* tok_slot = (int*)take(2 * N_TOK * 4);
  (void)ws_size; (void)in_sizes; (void)n_in; (void)out_size;

  hipFuncSetAttribute(reinterpret_cast<const void*>(&gemm8<true, unsigned short>),
                      hipFuncAttributeMaxDynamicSharedMemorySize, 131072);
  hipFuncSetAttribute(reinterpret_cast<const void*>(&gemm8<false, float>),
                      hipFuncAttributeMaxDynamicSharedMemorySize, 131072);

  init_kernel<<<1, 64, 0, stream>>>(counts, Psum);
  router_kernel<<<N_TOK / 16, 256, 0, stream>>>(x, Wr, counts, Psum, tok_e, tok_g, tok_ls);
  transpose_cvt<<<dim3(DFF / 64, DM / 64, NE), 256, 0, stream>>>(W1, W1T, DM, DFF);
  transpose_cvt<<<dim3(DM / 64, DFF / 64, NE), 256, 0, stream>>>(W2, W2T, DFF, DM);
  offsets_kernel<<<1, 64, 0, stream>>>(counts, Psum, offs, out + (size_t)N_TOK * DM);
  gather_kernel<<<N_TOK, 256, 0, stream>>>(x, tok_e, tok_ls, offs, tok_slot, Xg);
  gemm8<true, unsigned short><<<dim3(DFF / 256, 32, NE), 512, 131072, stream>>>(
      Xg, W1T, b1, H, offs, counts, DM, DFF);
  gemm8<false, float><<<dim3(DM / 256, 32, NE), 512, 131072, stream>>>(
      H, W2T, b2, Y, offs, counts, DFF, DM);
  combine_kernel<<<N_TOK, 256, 0, stream>>>(Y, tok_slot, tok_g, out);
}

// Round 4
// 753.477 us; speedup vs baseline: 1.2551x; 1.0684x over previous
//
#include <hip/hip_runtime.h>
#include <cstdint>
#include <cstddef>

#define N_TOK 8192
#define DM 1024
#define DFF 4096
#define NE 8
#define PAD 256
#define CAP (N_TOK * 2 + NE * PAD)  // 18432

typedef __attribute__((ext_vector_type(8))) short bf16x8;
typedef __attribute__((ext_vector_type(4))) float f32x4;

__device__ __forceinline__ unsigned short f2bf(float f) {
  union { float f; unsigned u; } v; v.f = f;
  unsigned r = v.u + 0x7FFFu + ((v.u >> 16) & 1u);
  return (unsigned short)(r >> 16);
}

__device__ __forceinline__ void async16(unsigned short* l, const unsigned short* g) {
  __builtin_amdgcn_global_load_lds(
      (const __attribute__((address_space(1))) unsigned int*)g,
      (__attribute__((address_space(3))) unsigned int*)l, 16, 0, 0);
}

// ---------------- init ----------------
__global__ void init_kernel(unsigned* counts, float* Psum) {
  int i = threadIdx.x;
  if (i < NE) { counts[i] = 0u; Psum[i] = 0.f; }
}

// ---------------- transpose + fp32->bf16 convert ----------------
__global__ __launch_bounds__(256) void transpose_cvt(
    const float* __restrict__ in, unsigned short* __restrict__ out, int R, int C) {
  __shared__ float tile[64][65];
  const float* I = in + (size_t)blockIdx.z * R * C;
  unsigned short* O = out + (size_t)blockIdx.z * R * C;
  const int r0 = blockIdx.y * 64, c0 = blockIdx.x * 64;
  const int c = threadIdx.x & 63, r4 = threadIdx.x >> 6;
#pragma unroll
  for (int i = 0; i < 16; ++i) {
    int r = r4 * 16 + i;
    tile[r][c] = I[(size_t)(r0 + r) * C + c0 + c];
  }
  __syncthreads();
#pragma unroll
  for (int i = 0; i < 16; ++i) {
    int r = r4 * 16 + i;
    O[(size_t)(c0 + r) * R + r0 + c] = f2bf(tile[c][r]);
  }
}

// ---------------- router ----------------
__global__ __launch_bounds__(256) void router_kernel(
    const float* __restrict__ x, const float* __restrict__ Wr,
    unsigned* __restrict__ counts, float* __restrict__ Psum,
    int* __restrict__ tok_e, float* __restrict__ tok_g, int* __restrict__ tok_ls) {
  __shared__ float ps[NE];
  const int tid = threadIdx.x;
  if (tid < NE) ps[tid] = 0.f;
  __syncthreads();
  const int lane = tid & 63, wid = tid >> 6;
  for (int u = 0; u < 4; ++u) {
    const int t = blockIdx.x * 16 + wid * 4 + u;
    float a[NE];
#pragma unroll
    for (int e = 0; e < NE; ++e) a[e] = 0.f;
#pragma unroll
    for (int i = 0; i < 16; ++i) {
      const int d = i * 64 + lane;
      const float xv = x[(size_t)t * DM + d];
      const float* wr = &Wr[(size_t)d * NE];
#pragma unroll
      for (int e = 0; e < NE; ++e) a[e] = fmaf(xv, wr[e], a[e]);
    }
#pragma unroll
    for (int e = 0; e < NE; ++e)
      for (int s = 32; s > 0; s >>= 1) a[e] += __shfl_xor(a[e], s);
    float mx = a[0];
#pragma unroll
    for (int e = 1; e < NE; ++e) mx = fmaxf(mx, a[e]);
    float p[NE], s = 0.f;
#pragma unroll
    for (int e = 0; e < NE; ++e) { p[e] = expf(a[e] - mx); s += p[e]; }
    float q[NE];
#pragma unroll
    for (int e = 0; e < NE; ++e) q[e] = p[e] / s;
    int i0 = 0; float b0 = q[0];
#pragma unroll
    for (int e = 1; e < NE; ++e) if (q[e] > b0) { b0 = q[e]; i0 = e; }
    int i1 = -1; float b1v = -1.f;
#pragma unroll
    for (int e = 0; e < NE; ++e) if (e != i0 && q[e] > b1v) { b1v = q[e]; i1 = e; }
    const float gs = q[i0] + q[i1];
    const float g0 = q[i0] / gs, g1 = q[i1] / gs;
    if (lane == 0) {
#pragma unroll
      for (int e = 0; e < NE; ++e) atomicAdd(&ps[e], q[e]);
      const int ls0 = (int)atomicAdd(&counts[i0], 1u);
      const int ls1 = (int)atomicAdd(&counts[i1], 1u);
      tok_e[2 * t] = i0; tok_e[2 * t + 1] = i1;
      tok_g[2 * t] = g0; tok_g[2 * t + 1] = g1;
      tok_ls[2 * t] = ls0; tok_ls[2 * t + 1] = ls1;
    }
  }
  __syncthreads();
  if (tid < NE) atomicAdd(&Psum[tid], ps[tid]);
}

// ---------------- offsets (256-padded prefix) + aux loss ----------------
__global__ void offsets_kernel(const unsigned* __restrict__ counts,
                               const float* __restrict__ Psum,
                               int* __restrict__ offs, float* __restrict__ aux_out) {
  if (threadIdx.x == 0 && blockIdx.x == 0) {
    int o = 0; float aux = 0.f;
    for (int e = 0; e < NE; ++e) {
      offs[e] = o;
      o += (int)((counts[e] + (PAD - 1u)) / PAD) * PAD;
      aux += ((float)counts[e] / (float)N_TOK) * (Psum[e] / (float)N_TOK);
    }
    aux_out[0] = 0.01f * (float)NE * aux;
  }
}

// ---------------- gather ----------------
__global__ __launch_bounds__(256) void gather_kernel(
    const float* __restrict__ x, const int* __restrict__ tok_e,
    const int* __restrict__ tok_ls, const int* __restrict__ offs,
    int* __restrict__ tok_slot, unsigned short* __restrict__ Xg) {
  const int t = blockIdx.x;
  __shared__ int ss[2];
  if (threadIdx.x < 2) {
    const int k = threadIdx.x;
    const int e = tok_e[2 * t + k];
    const int sl = offs[e] + tok_ls[2 * t + k];
    ss[k] = sl;
    tok_slot[2 * t + k] = sl;
  }
  __syncthreads();
  const int i = threadIdx.x;
  const float4 v = ((const float4*)x)[(size_t)t * 256 + i];
  ushort4 h;
  h.x = f2bf(v.x); h.y = f2bf(v.y); h.z = f2bf(v.z); h.w = f2bf(v.w);
  ((ushort4*)Xg)[(size_t)ss[0] * 256 + i] = h;
  ((ushort4*)Xg)[(size_t)ss[1] * 256 + i] = h;
}

// ---------------- 8-phase 256x256 GEMM (T2+T3+T4+T5), optional split-K ----------------
// C(rows x Nn) = A(rows x K) * Bt(Nn x K)^T + bias. 512 thr = 8 waves (2M x 4N).
// LDS (dynamic 128KB): per matrix [2 dbuf][2 k-slice][256 rows][32 cols bf16],
// 16B chunks XOR-swizzled by ((row>>1)&3)  [64B rows: bank pos = (R&1,chunk) ->
// need bijection over 8 consecutive rows; verified p={0,64,16,80,32,96,48,112}].
// Inverse swizzle applied on global src (rule #21). Stage slots within tile j:
//  p0: A-s1(j+1)  p1: B-s1(j+1)  p2: A-s0(j+2)  p3: B-s0(j+2); vmcnt(8) at p1/p3.
// SPLIT=2: blockIdx.z encodes (half, e); each half does K/2, bias only half 0,
// C offset by c_split_stride; combine sums the two halves.
template <int SPLIT, bool GELU, typename CT>
__global__ __launch_bounds__(512, 2) void gemm8(
    const unsigned short* __restrict__ Ag, const unsigned short* __restrict__ Bt,
    const float* __restrict__ bias, CT* __restrict__ Cout,
    const int* __restrict__ offs, const unsigned* __restrict__ counts,
    const int K, const int Nn, const size_t c_split_stride) {
  const int z = blockIdx.z;
  const int e = z & (NE - 1);
  const int ks = (SPLIT == 1) ? 0 : (z >> 3);
  const unsigned cnt = counts[e];
  const int tm = blockIdx.y;
  if ((unsigned)(tm * 256) >= cnt) return;
  const int tn = blockIdx.x;
  const int row0 = offs[e] + tm * 256;
  const int kext = K / SPLIT;
  const int nt = kext >> 6;

  const unsigned short* A = Ag + (size_t)row0 * K + (size_t)ks * kext;
  const unsigned short* B = Bt + ((size_t)e * Nn + (size_t)tn * 256) * K + (size_t)ks * kext;
  const float* bp = (ks == 0) ? bias : nullptr;
  CT* Cw = Cout + (size_t)ks * c_split_stride;

  extern __shared__ unsigned short lds[];
  unsigned short* LA = lds;           // 32768 shorts
  unsigned short* LB = lds + 32768;

  const int tid = threadIdx.x;
  const int lane = tid & 63;
  const int wid = tid >> 6;
  const int wm = wid >> 2;   // 0..1
  const int wn = wid & 3;    // 0..3
  const int arow = lane & 15;
  const int kc = lane >> 4;  // 16B chunk within 32-col slice

  f32x4 acc[8][4];
#pragma unroll
  for (int m = 0; m < 8; ++m)
#pragma unroll
    for (int n = 0; n < 4; ++n) acc[m][n] = (f32x4){0.f, 0.f, 0.f, 0.f};

  auto stage = [&](unsigned short* Lb, const unsigned short* G, int db, int sl, int kt) {
    unsigned short* hb = Lb + ((db * 2 + sl) << 13);
#pragma unroll
    for (int it = 0; it < 2; ++it) {
      const int c = it * 512 + tid;
      const int r = c >> 2;
      const int k4 = c & 3;
      const unsigned short* src =
          G + (size_t)r * K + kt * 64 + sl * 32 + ((k4 ^ ((r >> 1) & 3)) << 3);
      async16(hb + (size_t)(it * 512 + wid * 64) * 8, src);
    }
  };
  auto ldA = [&](int db, int sl, int mf) -> bf16x8 {
    const int R = wm * 128 + mf * 16 + arow;
    return *(const bf16x8*)&LA[((db * 2 + sl) << 13) + R * 32 + ((kc ^ ((R >> 1) & 3)) << 3)];
  };
  auto ldB = [&](int db, int sl, int nf) -> bf16x8 {
    const int R = wn * 64 + nf * 16 + arow;
    return *(const bf16x8*)&LB[((db * 2 + sl) << 13) + R * 32 + ((kc ^ ((R >> 1) & 3)) << 3)];
  };

  // prologue: T0 all 4 halves + T1 s0 halves
  stage(LA, A, 0, 0, 0);
  stage(LB, B, 0, 0, 0);
  stage(LA, A, 0, 1, 0);
  stage(LB, B, 0, 1, 0);
  stage(LA, A, 1, 0, 1);
  stage(LB, B, 1, 0, 1);
  asm volatile("s_waitcnt vmcnt(8)");
  __builtin_amdgcn_sched_barrier(0);
  __builtin_amdgcn_s_barrier();

  bf16x8 bfr[4];
  for (int j = 0; j < nt; ++j) {
    const int db = j & 1;
    const int dbn = db ^ 1;
    const int j1 = (j + 1 < nt) ? j + 1 : 0;  // clamped src; dest region is dead
    const int j2 = (j + 2 < nt) ? j + 2 : 0;
    bf16x8 afr[4];

    // ---- phase 0: (s0, q0); stage A-s1 of T(j+1)
#pragma unroll
    for (int n = 0; n < 4; ++n) bfr[n] = ldB(db, 0, n);
#pragma unroll
    for (int i = 0; i < 4; ++i) afr[i] = ldA(db, 0, i);
    stage(LA, A, dbn, 1, j1);
    __builtin_amdgcn_sched_barrier(0);
    __builtin_amdgcn_s_barrier();
    asm volatile("s_waitcnt lgkmcnt(0)");
    __builtin_amdgcn_sched_barrier(0);
    __builtin_amdgcn_s_setprio(1);
#pragma unroll
    for (int i = 0; i < 4; ++i)
#pragma unroll
      for (int n = 0; n < 4; ++n)
        acc[i][n] = __builtin_amdgcn_mfma_f32_16x16x32_bf16(afr[i], bfr[n], acc[i][n], 0, 0, 0);
    __builtin_amdgcn_s_setprio(0);
    __builtin_amdgcn_sched_barrier(0);
    __builtin_amdgcn_s_barrier();

    // ---- phase 1: (s0, q1); stage B-s1 of T(j+1); vmcnt
#pragma unroll
    for (int i = 0; i < 4; ++i) afr[i] = ldA(db, 0, 4 + i);
    stage(LB, B, dbn, 1, j1);
    asm volatile("s_waitcnt vmcnt(8)");
    __builtin_amdgcn_sched_barrier(0);
    __builtin_amdgcn_s_barrier();
    asm volatile("s_waitcnt lgkmcnt(0)");
    __builtin_amdgcn_sched_barrier(0);
    __builtin_amdgcn_s_setprio(1);
#pragma unroll
    for (int i = 0; i < 4; ++i)
#pragma unroll
      for (int n = 0; n < 4; ++n)
        acc[4 + i][n] = __builtin_amdgcn_mfma_f32_16x16x32_bf16(afr[i], bfr[n], acc[4 + i][n], 0, 0, 0);
    __builtin_amdgcn_s_setprio(0);
    __builtin_amdgcn_sched_barrier(0);
    __builtin_amdgcn_s_barrier();

    // ---- phase 2: (s1, q0); stage A-s0 of T(j+2)
#pragma unroll
    for (int n = 0; n < 4; ++n) bfr[n] = ldB(db, 1, n);
#pragma unroll
    for (int i = 0; i < 4; ++i) afr[i] = ldA(db, 1, i);
    stage(LA, A, db, 0, j2);
    __builtin_amdgcn_sched_barrier(0);
    __builtin_amdgcn_s_barrier();
    asm volatile("s_waitcnt lgkmcnt(0)");
    __builtin_amdgcn_sched_barrier(0);
    __builtin_amdgcn_s_setprio(1);
#pragma unroll
    for (int i = 0; i < 4; ++i)
#pragma unroll
      for (int n = 0; n < 4; ++n)
        acc[i][n] = __builtin_amdgcn_mfma_f32_16x16x32_bf16(afr[i], bfr[n], acc[i][n], 0, 0, 0);
    __builtin_amdgcn_s_setprio(0);
    __builtin_amdgcn_sched_barrier(0);
    __builtin_amdgcn_s_barrier();

    // ---- phase 3: (s1, q1); stage B-s0 of T(j+2); vmcnt
#pragma unroll
    for (int i = 0; i < 4; ++i) afr[i] = ldA(db, 1, 4 + i);
    stage(LB, B, db, 0, j2);
    asm volatile("s_waitcnt vmcnt(8)");
    __builtin_amdgcn_sched_barrier(0);
    __builtin_amdgcn_s_barrier();
    asm volatile("s_waitcnt lgkmcnt(0)");
    __builtin_amdgcn_sched_barrier(0);
    __builtin_amdgcn_s_setprio(1);
#pragma unroll
    for (int i = 0; i < 4; ++i)
#pragma unroll
      for (int n = 0; n < 4; ++n)
        acc[4 + i][n] = __builtin_amdgcn_mfma_f32_16x16x32_bf16(afr[i], bfr[n], acc[4 + i][n], 0, 0, 0);
    __builtin_amdgcn_s_setprio(0);
    __builtin_amdgcn_sched_barrier(0);
    __builtin_amdgcn_s_barrier();
  }

  // epilogue: n innermost so each 128B line is completed in 4 back-to-back
  // stores (kills partial-line RMW eviction traffic seen in R3).
  const int rl = (lane >> 4) * 4;
  const int cl = lane & 15;
  float bv[4];
#pragma unroll
  for (int n = 0; n < 4; ++n) {
    const int col = tn * 256 + wn * 64 + n * 16 + cl;
    bv[n] = bp ? bp[(size_t)e * Nn + col] : 0.f;
  }
#pragma unroll
  for (int m = 0; m < 8; ++m) {
    const int row = row0 + wm * 128 + m * 16 + rl;
#pragma unroll
    for (int jj = 0; jj < 4; ++jj) {
      CT* rowp = Cw + (size_t)(row + jj) * Nn + tn * 256 + wn * 64 + cl;
#pragma unroll
      for (int n = 0; n < 4; ++n) {
        float v = acc[m][n][jj] + bv[n];
        if (GELU) v = 0.5f * v * (1.f + erff(v * 0.70710678118654752f));
        if constexpr (sizeof(CT) == 2) { rowp[n * 16] = (CT)f2bf(v); } else { rowp[n * 16] = (CT)v; }
      }
    }
  }
}

// ---------------- combine: out[t] = g0*(Ya+Yb)[s0] + g1*(Ya+Yb)[s1] ----------------
__global__ __launch_bounds__(256) void combine_kernel(
    const float* __restrict__ Ya, const float* __restrict__ Yb,
    const int* __restrict__ tok_slot, const float* __restrict__ tok_g,
    float* __restrict__ out) {
  const int t = blockIdx.x;
  const int i = threadIdx.x;
  const int s0 = tok_slot[2 * t], s1 = tok_slot[2 * t + 1];
  const float g0 = tok_g[2 * t], g1 = tok_g[2 * t + 1];
  const float4 a0 = ((const float4*)Ya)[(size_t)s0 * 256 + i];
  const float4 b0 = ((const float4*)Yb)[(size_t)s0 * 256 + i];
  const float4 a1 = ((const float4*)Ya)[(size_t)s1 * 256 + i];
  const float4 b1 = ((const float4*)Yb)[(size_t)s1 * 256 + i];
  float4 r;
  r.x = g0 * (a0.x + b0.x) + g1 * (a1.x + b1.x);
  r.y = g0 * (a0.y + b0.y) + g1 * (a1.y + b1.y);
  r.z = g0 * (a0.z + b0.z) + g1 * (a1.z + b1.z);
  r.w = g0 * (a0.w + b0.w) + g1 * (a1.w + b1.w);
  ((float4*)out)[(size_t)t * 256 + i] = r;
}

extern "C" void kernel_launch(void* const* d_in, const int* in_sizes, int n_in,
                              void* d_out, int out_size, void* d_ws, size_t ws_size,
                              hipStream_t stream) {
  const float* x = (const float*)d_in[0];
  const float* Wr = (const float*)d_in[1];
  const float* W1 = (const float*)d_in[2];
  const float* b1 = (const float*)d_in[3];
  const float* W2 = (const float*)d_in[4];
  const float* b2 = (const float*)d_in[5];
  float* out = (float*)d_out;

  char* w = (char*)d_ws;
  size_t ob = 0;
  auto take = [&](size_t nbytes) -> void* {
    void* p = w + ob;
    ob = (ob + nbytes + 255) & ~(size_t)255;
    return p;
  };
  // Overlap: {W1T,Xg} (dead after GEMM1) share a region with {Ya,Yb}
  unsigned short* W2T = (unsigned short*)take((size_t)NE * DM * DFF * 2);   // 64MB
  unsigned short* H = (unsigned short*)take((size_t)CAP * DFF * 2);         // 151MB
  char* R = (char*)take(2 * (size_t)CAP * DM * 4);                          // 151MB
  unsigned short* W1T = (unsigned short*)R;                                 // 64MB
  unsigned short* Xg = (unsigned short*)(R + (size_t)NE * DFF * DM * 2);    // 37.75MB
  float* Ya = (float*)R;                                                    // 75.5MB
  float* Yb = (float*)(R + (size_t)CAP * DM * 4);                           // 75.5MB
  unsigned* counts = (unsigned*)take(NE * 4);
  float* Psum = (float*)take(NE * 4);
  int* offs = (int*)take(NE * 4);
  int* tok_e = (int*)take(2 * N_TOK * 4);
  float* tok_g = (float*)take(2 * N_TOK * 4);
  int* tok_ls = (int*)take(2 * N_TOK * 4);
  int* tok_slot = (int*)take(2 * N_TOK * 4);
  (void)ws_size; (void)in_sizes; (void)n_in; (void)out_size;

  hipFuncSetAttribute(reinterpret_cast<const void*>(&gemm8<1, true, unsigned short>),
                      hipFuncAttributeMaxDynamicSharedMemorySize, 131072);
  hipFuncSetAttribute(reinterpret_cast<const void*>(&gemm8<2, false, float>),
                      hipFuncAttributeMaxDynamicSharedMemorySize, 131072);

  init_kernel<<<1, 64, 0, stream>>>(counts, Psum);
  router_kernel<<<N_TOK / 16, 256, 0, stream>>>(x, Wr, counts, Psum, tok_e, tok_g, tok_ls);
  transpose_cvt<<<dim3(DFF / 64, DM / 64, NE), 256, 0, stream>>>(W1, W1T, DM, DFF);
  transpose_cvt<<<dim3(DM / 64, DFF / 64, NE), 256, 0, stream>>>(W2, W2T, DFF, DM);
  offsets_kernel<<<1, 64, 0, stream>>>(counts, Psum, offs, out + (size_t)N_TOK * DM);
  gather_kernel<<<N_TOK, 256, 0, stream>>>(x, tok_e, tok_ls, offs, tok_slot, Xg);
  // GEMM1: H = gelu(Xg @ W1 + b1)
  gemm8<1, true, unsigned short><<<dim3(DFF / 256, 32, NE), 512, 131072, stream>>>(
      Xg, W1T, b1, H, offs, counts, DM, DFF, 0);
  // GEMM2 split-K=2 in one dispatch: z = (half<<3)|e; halves write Ya / Yb
  gemm8<2, false, float><<<dim3(DM / 256, 32, 2 * NE), 512, 131072, stream>>>(
      H, W2T, b2, Ya, offs, counts, DFF, DM, (size_t)CAP * DM);
  combine_kernel<<<N_TOK, 256, 0, stream>>>(Ya, Yb, tok_slot, tok_g, out);
}

// Round 5
// 738.196 us; speedup vs baseline: 1.2811x; 1.0207x over previous
//
#include <hip/hip_runtime.h>
#include <cstdint>
#include <cstddef>

#define N_TOK 8192
#define DM 1024
#define DFF 4096
#define NE 8
#define PAD 256
#define CAP (N_TOK * 2 + NE * PAD)  // 18432

typedef __attribute__((ext_vector_type(8))) short bf16x8;
typedef __attribute__((ext_vector_type(4))) float f32x4;

__device__ __forceinline__ unsigned short f2bf(float f) {
  union { float f; unsigned u; } v; v.f = f;
  unsigned r = v.u + 0x7FFFu + ((v.u >> 16) & 1u);
  return (unsigned short)(r >> 16);
}

__device__ __forceinline__ void async16(unsigned short* l, const unsigned short* g) {
  __builtin_amdgcn_global_load_lds(
      (const __attribute__((address_space(1))) unsigned int*)g,
      (__attribute__((address_space(3))) unsigned int*)l, 16, 0, 0);
}

// ---------------- init ----------------
__global__ void init_kernel(unsigned* counts, float* Psum) {
  int i = threadIdx.x;
  if (i < NE) { counts[i] = 0u; Psum[i] = 0.f; }
}

// ---------------- transpose + fp32->bf16 convert ----------------
__global__ __launch_bounds__(256) void transpose_cvt(
    const float* __restrict__ in, unsigned short* __restrict__ out, int R, int C) {
  __shared__ float tile[64][65];
  const float* I = in + (size_t)blockIdx.z * R * C;
  unsigned short* O = out + (size_t)blockIdx.z * R * C;
  const int r0 = blockIdx.y * 64, c0 = blockIdx.x * 64;
  const int c = threadIdx.x & 63, r4 = threadIdx.x >> 6;
#pragma unroll
  for (int i = 0; i < 16; ++i) {
    int r = r4 * 16 + i;
    tile[r][c] = I[(size_t)(r0 + r) * C + c0 + c];
  }
  __syncthreads();
#pragma unroll
  for (int i = 0; i < 16; ++i) {
    int r = r4 * 16 + i;
    O[(size_t)(c0 + r) * R + r0 + c] = f2bf(tile[c][r]);
  }
}

// ---------------- router ----------------
__global__ __launch_bounds__(256) void router_kernel(
    const float* __restrict__ x, const float* __restrict__ Wr,
    unsigned* __restrict__ counts, float* __restrict__ Psum,
    int* __restrict__ tok_e, float* __restrict__ tok_g, int* __restrict__ tok_ls) {
  __shared__ float ps[NE];
  const int tid = threadIdx.x;
  if (tid < NE) ps[tid] = 0.f;
  __syncthreads();
  const int lane = tid & 63, wid = tid >> 6;
  for (int u = 0; u < 4; ++u) {
    const int t = blockIdx.x * 16 + wid * 4 + u;
    float a[NE];
#pragma unroll
    for (int e = 0; e < NE; ++e) a[e] = 0.f;
#pragma unroll
    for (int i = 0; i < 16; ++i) {
      const int d = i * 64 + lane;
      const float xv = x[(size_t)t * DM + d];
      const float* wr = &Wr[(size_t)d * NE];
#pragma unroll
      for (int e = 0; e < NE; ++e) a[e] = fmaf(xv, wr[e], a[e]);
    }
#pragma unroll
    for (int e = 0; e < NE; ++e)
      for (int s = 32; s > 0; s >>= 1) a[e] += __shfl_xor(a[e], s);
    float mx = a[0];
#pragma unroll
    for (int e = 1; e < NE; ++e) mx = fmaxf(mx, a[e]);
    float p[NE], s = 0.f;
#pragma unroll
    for (int e = 0; e < NE; ++e) { p[e] = expf(a[e] - mx); s += p[e]; }
    float q[NE];
#pragma unroll
    for (int e = 0; e < NE; ++e) q[e] = p[e] / s;
    int i0 = 0; float b0 = q[0];
#pragma unroll
    for (int e = 1; e < NE; ++e) if (q[e] > b0) { b0 = q[e]; i0 = e; }
    int i1 = -1; float b1v = -1.f;
#pragma unroll
    for (int e = 0; e < NE; ++e) if (e != i0 && q[e] > b1v) { b1v = q[e]; i1 = e; }
    const float gs = q[i0] + q[i1];
    const float g0 = q[i0] / gs, g1 = q[i1] / gs;
    if (lane == 0) {
#pragma unroll
      for (int e = 0; e < NE; ++e) atomicAdd(&ps[e], q[e]);
      const int ls0 = (int)atomicAdd(&counts[i0], 1u);
      const int ls1 = (int)atomicAdd(&counts[i1], 1u);
      tok_e[2 * t] = i0; tok_e[2 * t + 1] = i1;
      tok_g[2 * t] = g0; tok_g[2 * t + 1] = g1;
      tok_ls[2 * t] = ls0; tok_ls[2 * t + 1] = ls1;
    }
  }
  __syncthreads();
  if (tid < NE) atomicAdd(&Psum[tid], ps[tid]);
}

// ---------------- offsets (256-padded prefix) + aux loss ----------------
__global__ void offsets_kernel(const unsigned* __restrict__ counts,
                               const float* __restrict__ Psum,
                               int* __restrict__ offs, float* __restrict__ aux_out) {
  if (threadIdx.x == 0 && blockIdx.x == 0) {
    int o = 0; float aux = 0.f;
    for (int e = 0; e < NE; ++e) {
      offs[e] = o;
      o += (int)((counts[e] + (PAD - 1u)) / PAD) * PAD;
      aux += ((float)counts[e] / (float)N_TOK) * (Psum[e] / (float)N_TOK);
    }
    aux_out[0] = 0.01f * (float)NE * aux;
  }
}

// ---------------- gather ----------------
__global__ __launch_bounds__(256) void gather_kernel(
    const float* __restrict__ x, const int* __restrict__ tok_e,
    const int* __restrict__ tok_ls, const int* __restrict__ offs,
    int* __restrict__ tok_slot, unsigned short* __restrict__ Xg) {
  const int t = blockIdx.x;
  __shared__ int ss[2];
  if (threadIdx.x < 2) {
    const int k = threadIdx.x;
    const int e = tok_e[2 * t + k];
    const int sl = offs[e] + tok_ls[2 * t + k];
    ss[k] = sl;
    tok_slot[2 * t + k] = sl;
  }
  __syncthreads();
  const int i = threadIdx.x;
  const float4 v = ((const float4*)x)[(size_t)t * 256 + i];
  ushort4 h;
  h.x = f2bf(v.x); h.y = f2bf(v.y); h.z = f2bf(v.z); h.w = f2bf(v.w);
  ((ushort4*)Xg)[(size_t)ss[0] * 256 + i] = h;
  ((ushort4*)Xg)[(size_t)ss[1] * 256 + i] = h;
}

// ---------------- 8-phase 256x256 GEMM, de-pinned schedule ----------------
// C(rows x Nn) = A(rows x K) * Bt(Nn x K)^T + bias. 512 thr = 8 waves (2M x 4N).
// LDS 128KB: per matrix 4 regions [db(2)][slice(2)] of 256 rows x 32 cols bf16;
// 16B chunks XOR-swizzled by ((row>>1)&3) both sides (conflict-free, R4-verified).
// ONE barrier per phase; vmcnt(8) (mem-clobbered) at end of p1/p3 only; no
// lgkmcnt drains (plain-C++ ds_reads -> compiler emits fine-grained waits and
// overlaps ds_read tail with MFMA head). Ledger (loads, 2 per stage call):
//  s1(j) staged p0/p1(j-1) = loads 8j+5..8j+8; vmcnt(8)@p1(j) -> done thru 8j+8.
//  s0(j+1) staged p2/p3(j-1) = loads 8j+9..8j+12; vmcnt(8)@p3(j) -> thru 8j+12.
// Every read-vs-overwrite pair separated by >=1 memory-clobbered s_barrier.
// SPLIT=2: blockIdx.y encodes (half, e); grid z = tm (supports <=4096 rows/expert).
template <int SPLIT, bool GELU, typename CT>
__global__ __launch_bounds__(512, 2) void gemm8(
    const unsigned short* __restrict__ Ag, const unsigned short* __restrict__ Bt,
    const float* __restrict__ bias, CT* __restrict__ Cout,
    const int* __restrict__ offs, const unsigned* __restrict__ counts,
    const int K, const int Nn, const size_t c_split_stride) {
  const int e = (int)blockIdx.y & (NE - 1);
  const int ks = (SPLIT == 1) ? 0 : ((int)blockIdx.y >> 3);
  const unsigned cnt = counts[e];
  const int tm = blockIdx.z;
  if ((unsigned)(tm * 256) >= cnt) return;
  const int tn = blockIdx.x;
  const int row0 = offs[e] + tm * 256;
  const int kext = K / SPLIT;
  const int nt = kext >> 6;

  const unsigned short* A = Ag + (size_t)row0 * K + (size_t)ks * kext;
  const unsigned short* B = Bt + ((size_t)e * Nn + (size_t)tn * 256) * K + (size_t)ks * kext;
  const float* bp = (ks == 0) ? bias : nullptr;
  CT* Cw = Cout + (size_t)ks * c_split_stride;

  extern __shared__ unsigned short lds[];
  unsigned short* LA = lds;           // 4 regions x 8192 shorts
  unsigned short* LB = lds + 32768;

  const int tid = threadIdx.x;
  const int lane = tid & 63;
  const int wid = tid >> 6;
  const int wm = wid >> 2;   // 0..1
  const int wn = wid & 3;    // 0..3
  const int arow = lane & 15;
  const int kc = lane >> 4;

  // hoisted per-thread addressing -------------------------------------------
  // LDS read offsets (shorts): swizzle term is per-thread constant.
  const int swr = (kc ^ ((arow >> 1) & 3)) << 3;
  int aoff[8], boff[4];
#pragma unroll
  for (int mf = 0; mf < 8; ++mf) aoff[mf] = (wm * 128 + mf * 16 + arow) * 32 + swr;
#pragma unroll
  for (int nf = 0; nf < 4; ++nf) boff[nf] = (wn * 64 + nf * 16 + arow) * 32 + swr;
  // stage: thread -> chunk (it*512+tid); row r = it*128 + (tid>>2); swizzle
  // (tid&3)^((tid>>3)&3) is it-invariant (128 = 0 mod 8).
  const int sswz = ((tid & 3) ^ ((tid >> 3) & 3)) << 3;
  const unsigned short* sA = A + (size_t)(tid >> 2) * K + sswz;
  const unsigned short* sB = B + (size_t)(tid >> 2) * K + sswz;
  const size_t rstep = (size_t)128 * K;
  const size_t dst0 = (size_t)wid * 512;  // shorts; lane offset added by HW

  auto stage2 = [&](unsigned short* region, const unsigned short* sbase, int koff) {
    async16(region + dst0, sbase + koff);
    async16(region + 4096 + dst0, sbase + rstep + koff);
  };

  f32x4 acc[8][4];
#pragma unroll
  for (int m = 0; m < 8; ++m)
#pragma unroll
    for (int n = 0; n < 4; ++n) acc[m][n] = (f32x4){0.f, 0.f, 0.f, 0.f};

  // prologue: T0 {s0,s1} + T1 {s0}
  stage2(LA, sA, 0);
  stage2(LB, sB, 0);
  stage2(LA + (1 << 13), sA, 32);
  stage2(LB + (1 << 13), sB, 32);
  stage2(LA + (2 << 13), sA, 64);
  stage2(LB + (2 << 13), sB, 64);
  asm volatile("s_waitcnt vmcnt(8)" ::: "memory");
  asm volatile("s_barrier" ::: "memory");

  bf16x8 afr[4], bfr[4];
  for (int j = 0; j < nt; ++j) {
    const int db = j & 1;
    const int dbn = db ^ 1;
    const int k1 = ((j + 1 < nt) ? j + 1 : 0) << 6;  // clamped; dest region dead
    const int k2 = ((j + 2 < nt) ? j + 2 : 0) << 6;
    const int r0 = (db * 2) << 13;       // region (db, s0)
    const int r1 = (db * 2 + 1) << 13;   // region (db, s1)
    const int w1 = (dbn * 2 + 1) << 13;  // region (dbn, s1)

    // ---- p0: read s0 (B + A-lo); stage A-s1(j+1)
#pragma unroll
    for (int n = 0; n < 4; ++n) bfr[n] = *(const bf16x8*)&LB[r0 + boff[n]];
#pragma unroll
    for (int i = 0; i < 4; ++i) afr[i] = *(const bf16x8*)&LA[r0 + aoff[i]];
    stage2(LA + w1, sA, k1 + 32);
    __builtin_amdgcn_s_setprio(1);
#pragma unroll
    for (int i = 0; i < 4; ++i)
#pragma unroll
      for (int n = 0; n < 4; ++n)
        acc[i][n] = __builtin_amdgcn_mfma_f32_16x16x32_bf16(afr[i], bfr[n], acc[i][n], 0, 0, 0);
    __builtin_amdgcn_s_setprio(0);
    asm volatile("s_barrier" ::: "memory");

    // ---- p1: read s0 A-hi; stage B-s1(j+1); vmcnt
#pragma unroll
    for (int i = 0; i < 4; ++i) afr[i] = *(const bf16x8*)&LA[r0 + aoff[4 + i]];
    stage2(LB + w1, sB, k1 + 32);
    __builtin_amdgcn_s_setprio(1);
#pragma unroll
    for (int i = 0; i < 4; ++i)
#pragma unroll
      for (int n = 0; n < 4; ++n)
        acc[4 + i][n] = __builtin_amdgcn_mfma_f32_16x16x32_bf16(afr[i], bfr[n], acc[4 + i][n], 0, 0, 0);
    __builtin_amdgcn_s_setprio(0);
    asm volatile("s_waitcnt vmcnt(8)" ::: "memory");
    asm volatile("s_barrier" ::: "memory");

    // ---- p2: read s1 (B + A-lo); stage A-s0(j+2) into (db,s0)
#pragma unroll
    for (int n = 0; n < 4; ++n) bfr[n] = *(const bf16x8*)&LB[r1 + boff[n]];
#pragma unroll
    for (int i = 0; i < 4; ++i) afr[i] = *(const bf16x8*)&LA[r1 + aoff[i]];
    stage2(LA + r0, sA, k2);
    __builtin_amdgcn_s_setprio(1);
#pragma unroll
    for (int i = 0; i < 4; ++i)
#pragma unroll
      for (int n = 0; n < 4; ++n)
        acc[i][n] = __builtin_amdgcn_mfma_f32_16x16x32_bf16(afr[i], bfr[n], acc[i][n], 0, 0, 0);
    __builtin_amdgcn_s_setprio(0);
    asm volatile("s_barrier" ::: "memory");

    // ---- p3: read s1 A-hi; stage B-s0(j+2); vmcnt
#pragma unroll
    for (int i = 0; i < 4; ++i) afr[i] = *(const bf16x8*)&LA[r1 + aoff[4 + i]];
    stage2(LB + r0, sB, k2);
    __builtin_amdgcn_s_setprio(1);
#pragma unroll
    for (int i = 0; i < 4; ++i)
#pragma unroll
      for (int n = 0; n < 4; ++n)
        acc[4 + i][n] = __builtin_amdgcn_mfma_f32_16x16x32_bf16(afr[i], bfr[n], acc[4 + i][n], 0, 0, 0);
    __builtin_amdgcn_s_setprio(0);
    asm volatile("s_waitcnt vmcnt(8)" ::: "memory");
    asm volatile("s_barrier" ::: "memory");
  }
  asm volatile("s_waitcnt vmcnt(0)" ::: "memory");

  // epilogue: n innermost so each 128B line is completed back-to-back (no RMW).
  const int rl = (lane >> 4) * 4;
  const int cl = lane & 15;
  float bv[4];
#pragma unroll
  for (int n = 0; n < 4; ++n) {
    const int col = tn * 256 + wn * 64 + n * 16 + cl;
    bv[n] = bp ? bp[(size_t)e * Nn + col] : 0.f;
  }
#pragma unroll
  for (int m = 0; m < 8; ++m) {
    const int row = row0 + wm * 128 + m * 16 + rl;
#pragma unroll
    for (int jj = 0; jj < 4; ++jj) {
      CT* rowp = Cw + (size_t)(row + jj) * Nn + tn * 256 + wn * 64 + cl;
#pragma unroll
      for (int n = 0; n < 4; ++n) {
        float v = acc[m][n][jj] + bv[n];
        if (GELU) v = 0.5f * v * (1.f + erff(v * 0.70710678118654752f));
        if constexpr (sizeof(CT) == 2) { rowp[n * 16] = (CT)f2bf(v); } else { rowp[n * 16] = (CT)v; }
      }
    }
  }
}

// ---------------- combine: out[t] = g0*(Ya+Yb)[s0] + g1*(Ya+Yb)[s1] ----------------
__global__ __launch_bounds__(256) void combine_kernel(
    const float* __restrict__ Ya, const float* __restrict__ Yb,
    const int* __restrict__ tok_slot, const float* __restrict__ tok_g,
    float* __restrict__ out) {
  const int t = blockIdx.x;
  const int i = threadIdx.x;
  const int s0 = tok_slot[2 * t], s1 = tok_slot[2 * t + 1];
  const float g0 = tok_g[2 * t], g1 = tok_g[2 * t + 1];
  const float4 a0 = ((const float4*)Ya)[(size_t)s0 * 256 + i];
  const float4 b0 = ((const float4*)Yb)[(size_t)s0 * 256 + i];
  const float4 a1 = ((const float4*)Ya)[(size_t)s1 * 256 + i];
  const float4 b1 = ((const float4*)Yb)[(size_t)s1 * 256 + i];
  float4 r;
  r.x = g0 * (a0.x + b0.x) + g1 * (a1.x + b1.x);
  r.y = g0 * (a0.y + b0.y) + g1 * (a1.y + b1.y);
  r.z = g0 * (a0.z + b0.z) + g1 * (a1.z + b1.z);
  r.w = g0 * (a0.w + b0.w) + g1 * (a1.w + b1.w);
  ((float4*)out)[(size_t)t * 256 + i] = r;
}

extern "C" void kernel_launch(void* const* d_in, const int* in_sizes, int n_in,
                              void* d_out, int out_size, void* d_ws, size_t ws_size,
                              hipStream_t stream) {
  const float* x = (const float*)d_in[0];
  const float* Wr = (const float*)d_in[1];
  const float* W1 = (const float*)d_in[2];
  const float* b1 = (const float*)d_in[3];
  const float* W2 = (const float*)d_in[4];
  const float* b2 = (const float*)d_in[5];
  float* out = (float*)d_out;

  char* w = (char*)d_ws;
  size_t ob = 0;
  auto take = [&](size_t nbytes) -> void* {
    void* p = w + ob;
    ob = (ob + nbytes + 255) & ~(size_t)255;
    return p;
  };
  // Overlap: {W1T,Xg} (dead after GEMM1) share a region with {Ya,Yb}
  unsigned short* W2T = (unsigned short*)take((size_t)NE * DM * DFF * 2);   // 64MB
  unsigned short* H = (unsigned short*)take((size_t)CAP * DFF * 2);         // 151MB
  char* R = (char*)take(2 * (size_t)CAP * DM * 4);                          // 151MB
  unsigned short* W1T = (unsigned short*)R;                                 // 64MB
  unsigned short* Xg = (unsigned short*)(R + (size_t)NE * DFF * DM * 2);    // 37.75MB
  float* Ya = (float*)R;                                                    // 75.5MB
  float* Yb = (float*)(R + (size_t)CAP * DM * 4);                           // 75.5MB
  unsigned* counts = (unsigned*)take(NE * 4);
  float* Psum = (float*)take(NE * 4);
  int* offs = (int*)take(NE * 4);
  int* tok_e = (int*)take(2 * N_TOK * 4);
  float* tok_g = (float*)take(2 * N_TOK * 4);
  int* tok_ls = (int*)take(2 * N_TOK * 4);
  int* tok_slot = (int*)take(2 * N_TOK * 4);
  (void)ws_size; (void)in_sizes; (void)n_in; (void)out_size;

  hipFuncSetAttribute(reinterpret_cast<const void*>(&gemm8<1, true, unsigned short>),
                      hipFuncAttributeMaxDynamicSharedMemorySize, 131072);
  hipFuncSetAttribute(reinterpret_cast<const void*>(&gemm8<2, false, float>),
                      hipFuncAttributeMaxDynamicSharedMemorySize, 131072);

  init_kernel<<<1, 64, 0, stream>>>(counts, Psum);
  router_kernel<<<N_TOK / 16, 256, 0, stream>>>(x, Wr, counts, Psum, tok_e, tok_g, tok_ls);
  transpose_cvt<<<dim3(DFF / 64, DM / 64, NE), 256, 0, stream>>>(W1, W1T, DM, DFF);
  transpose_cvt<<<dim3(DM / 64, DFF / 64, NE), 256, 0, stream>>>(W2, W2T, DFF, DM);
  offsets_kernel<<<1, 64, 0, stream>>>(counts, Psum, offs, out + (size_t)N_TOK * DM);
  gather_kernel<<<N_TOK, 256, 0, stream>>>(x, tok_e, tok_ls, offs, tok_slot, Xg);
  // GEMM1: H = gelu(Xg @ W1 + b1); grid: x=tn, y=e, z=tm (empties cluster last)
  gemm8<1, true, unsigned short><<<dim3(DFF / 256, NE, 16), 512, 131072, stream>>>(
      Xg, W1T, b1, H, offs, counts, DM, DFF, 0);
  // GEMM2 split-K=2: y = (half<<3)|e; halves write Ya / Yb
  gemm8<2, false, float><<<dim3(DM / 256, 2 * NE, 16), 512, 131072, stream>>>(
      H, W2T, b2, Ya, offs, counts, DFF, DM, (size_t)CAP * DM);
  combine_kernel<<<N_TOK, 256, 0, stream>>>(Ya, Yb, tok_slot, tok_g, out);
}

// Round 6
// 701.406 us; speedup vs baseline: 1.3483x; 1.0525x over previous
//
#include <hip/hip_runtime.h>
#include <cstdint>
#include <cstddef>

#define N_TOK 8192
#define DM 1024
#define DFF 4096
#define NE 8
#define PAD 256
#define CAP (N_TOK * 2 + NE * PAD)  // 18432
#define TMG (CAP / 256)             // 72 global row-tiles

typedef __attribute__((ext_vector_type(8))) short bf16x8;
typedef __attribute__((ext_vector_type(4))) float f32x4;

__device__ __forceinline__ unsigned short f2bf(float f) {
  union { float f; unsigned u; } v; v.f = f;
  unsigned r = v.u + 0x7FFFu + ((v.u >> 16) & 1u);
  return (unsigned short)(r >> 16);
}

__device__ __forceinline__ void async16(unsigned short* l, const unsigned short* g) {
  __builtin_amdgcn_global_load_lds(
      (const __attribute__((address_space(1))) unsigned int*)g,
      (__attribute__((address_space(3))) unsigned int*)l, 16, 0, 0);
}

// ---------------- init ----------------
__global__ void init_kernel(unsigned* counts, float* Psum) {
  int i = threadIdx.x;
  if (i < NE) { counts[i] = 0u; Psum[i] = 0.f; }
}

// ---------------- transpose + fp32->bf16 convert ----------------
__global__ __launch_bounds__(256) void transpose_cvt(
    const float* __restrict__ in, unsigned short* __restrict__ out, int R, int C) {
  __shared__ float tile[64][65];
  const float* I = in + (size_t)blockIdx.z * R * C;
  unsigned short* O = out + (size_t)blockIdx.z * R * C;
  const int r0 = blockIdx.y * 64, c0 = blockIdx.x * 64;
  const int c = threadIdx.x & 63, r4 = threadIdx.x >> 6;
#pragma unroll
  for (int i = 0; i < 16; ++i) {
    int r = r4 * 16 + i;
    tile[r][c] = I[(size_t)(r0 + r) * C + c0 + c];
  }
  __syncthreads();
#pragma unroll
  for (int i = 0; i < 16; ++i) {
    int r = r4 * 16 + i;
    O[(size_t)(c0 + r) * R + r0 + c] = f2bf(tile[c][r]);
  }
}

// ---------------- router ----------------
__global__ __launch_bounds__(256) void router_kernel(
    const float* __restrict__ x, const float* __restrict__ Wr,
    unsigned* __restrict__ counts, float* __restrict__ Psum,
    int* __restrict__ tok_e, float* __restrict__ tok_g, int* __restrict__ tok_ls) {
  __shared__ float ps[NE];
  const int tid = threadIdx.x;
  if (tid < NE) ps[tid] = 0.f;
  __syncthreads();
  const int lane = tid & 63, wid = tid >> 6;
  for (int u = 0; u < 4; ++u) {
    const int t = blockIdx.x * 16 + wid * 4 + u;
    float a[NE];
#pragma unroll
    for (int e = 0; e < NE; ++e) a[e] = 0.f;
#pragma unroll
    for (int i = 0; i < 16; ++i) {
      const int d = i * 64 + lane;
      const float xv = x[(size_t)t * DM + d];
      const float* wr = &Wr[(size_t)d * NE];
#pragma unroll
      for (int e = 0; e < NE; ++e) a[e] = fmaf(xv, wr[e], a[e]);
    }
#pragma unroll
    for (int e = 0; e < NE; ++e)
      for (int s = 32; s > 0; s >>= 1) a[e] += __shfl_xor(a[e], s);
    float mx = a[0];
#pragma unroll
    for (int e = 1; e < NE; ++e) mx = fmaxf(mx, a[e]);
    float p[NE], s = 0.f;
#pragma unroll
    for (int e = 0; e < NE; ++e) { p[e] = expf(a[e] - mx); s += p[e]; }
    float q[NE];
#pragma unroll
    for (int e = 0; e < NE; ++e) q[e] = p[e] / s;
    int i0 = 0; float b0 = q[0];
#pragma unroll
    for (int e = 1; e < NE; ++e) if (q[e] > b0) { b0 = q[e]; i0 = e; }
    int i1 = -1; float b1v = -1.f;
#pragma unroll
    for (int e = 0; e < NE; ++e) if (e != i0 && q[e] > b1v) { b1v = q[e]; i1 = e; }
    const float gs = q[i0] + q[i1];
    const float g0 = q[i0] / gs, g1 = q[i1] / gs;
    if (lane == 0) {
#pragma unroll
      for (int e = 0; e < NE; ++e) atomicAdd(&ps[e], q[e]);
      const int ls0 = (int)atomicAdd(&counts[i0], 1u);
      const int ls1 = (int)atomicAdd(&counts[i1], 1u);
      tok_e[2 * t] = i0; tok_e[2 * t + 1] = i1;
      tok_g[2 * t] = g0; tok_g[2 * t + 1] = g1;
      tok_ls[2 * t] = ls0; tok_ls[2 * t + 1] = ls1;
    }
  }
  __syncthreads();
  if (tid < NE) atomicAdd(&Psum[tid], ps[tid]);
}

// ---------------- offsets (256-padded prefix) + total + aux loss ----------------
__global__ void offsets_kernel(const unsigned* __restrict__ counts,
                               const float* __restrict__ Psum,
                               int* __restrict__ offs, float* __restrict__ aux_out) {
  if (threadIdx.x == 0 && blockIdx.x == 0) {
    int o = 0; float aux = 0.f;
    for (int e = 0; e < NE; ++e) {
      offs[e] = o;
      o += (int)((counts[e] + (PAD - 1u)) / PAD) * PAD;
      aux += ((float)counts[e] / (float)N_TOK) * (Psum[e] / (float)N_TOK);
    }
    offs[NE] = o;  // total padded rows
    aux_out[0] = 0.01f * (float)NE * aux;
  }
}

// ---------------- gather ----------------
__global__ __launch_bounds__(256) void gather_kernel(
    const float* __restrict__ x, const int* __restrict__ tok_e,
    const int* __restrict__ tok_ls, const int* __restrict__ offs,
    int* __restrict__ tok_slot, unsigned short* __restrict__ Xg) {
  const int t = blockIdx.x;
  __shared__ int ss[2];
  if (threadIdx.x < 2) {
    const int k = threadIdx.x;
    const int e = tok_e[2 * t + k];
    const int sl = offs[e] + tok_ls[2 * t + k];
    ss[k] = sl;
    tok_slot[2 * t + k] = sl;
  }
  __syncthreads();
  const int i = threadIdx.x;
  const float4 v = ((const float4*)x)[(size_t)t * 256 + i];
  ushort4 h;
  h.x = f2bf(v.x); h.y = f2bf(v.y); h.z = f2bf(v.z); h.w = f2bf(v.w);
  ((ushort4*)Xg)[(size_t)ss[0] * 256 + i] = h;
  ((ushort4*)Xg)[(size_t)ss[1] * 256 + i] = h;
}

// ---------------- 8-phase 256x256 GEMM, half-tile staging (m201-converged) ----
// C(rows x Nn) = A(rows x K)*Bt(Nn x K)^T + bias. 512 thr = 8 waves (2M x 4N).
// LDS 128KB: per matrix 4 static regions [db(2)][half(2)] of 128 rows x 64 cols
// bf16 (db = K-tile parity, half = row-half). 16B chunks XOR-swizzled by (row&7)
// both sides (G4 formula; residual 2-way = free). Stage = 2 x async16/call,
// each lane reads one full 128B line (was 64B half-lines in R5).
// 8 phases per 2 K-tiles (T even, db0; T+1, db1), ONE barrier/phase, de-pinned:
//  p0: read bfr[nf01]x2k + afr[mf0-3]x2k (12), stage A-db1-h0(T+1), 16 MFMA
//  p1: read bfr[nf23] (4),                stage A-db1-h1(T+1), 16 MFMA
//  p2: read afr[mf4-7] (8),               stage B-db0-h0(T+2), 16 MFMA
//  p3: (0 reads; bfr nf01 kept live),     stage B-db0-h1(T+2), 16 MFMA, vmcnt(4)
//  p4-p7: same on db1/tile T+1; stages A-db0-h0/h1(T+2), B-db1-h0/h1(T+3), vmcnt(4)
// Region-free ledger: each stage call is >=1 barrier after its region's last
// ds_read (B freed after its 2 read-phases, A after p0/p2). vmcnt(4)@p3 confirms
// A-h1(T+1) [staged p1, read p4]; vmcnt(4)@p7 confirms all of T+2 [read next p0].
// Grid: y = global row-tile over concatenated padded slots (offs[NE] = total
// kills empty blocks); x = tn fast (A-panel shared, L2-local); z = split half.
template <int SPLIT, bool GELU, typename CT>
__global__ __launch_bounds__(512, 2) void gemm8(
    const unsigned short* __restrict__ Ag, const unsigned short* __restrict__ Bt,
    const float* __restrict__ bias, CT* __restrict__ Cout,
    const int* __restrict__ offs, const int K, const int Nn,
    const size_t c_split_stride) {
  const int gr = blockIdx.y;
  const int grow = gr * 256;
  if (grow >= offs[NE]) return;
  int e = 0;
#pragma unroll
  for (int k = 1; k < NE; ++k) if (offs[k] <= grow) e = k;
  const int ks = (SPLIT == 1) ? 0 : (int)blockIdx.z;
  const int tn = blockIdx.x;
  const int row0 = grow;
  const int kext = K / SPLIT;
  const int nt = kext >> 6;  // K-tiles of 64

  const unsigned short* A = Ag + (size_t)row0 * K + (size_t)ks * kext;
  const unsigned short* B = Bt + ((size_t)e * Nn + (size_t)tn * 256) * K + (size_t)ks * kext;
  const float* bp = (ks == 0) ? bias : nullptr;
  CT* Cw = Cout + (size_t)ks * c_split_stride;

  extern __shared__ unsigned short lds[];
  unsigned short* LA = lds;            // 4 regions x 8192 shorts
  unsigned short* LB = lds + 32768;
  const int REG = 8192;

  const int tid = threadIdx.x;
  const int lane = tid & 63;
  const int wid = tid >> 6;
  const int wm = wid >> 2;    // 0..1 -> A half
  const int wn = wid & 3;     // 0..3; B half = wn>>1
  const int wnh = wn >> 1;
  const int arow = lane & 15;
  const int kc = lane >> 4;   // 0..3

  // LDS read swizzle constants: chunk (s*4+kc) ^ (row&7); row&7 == arow&7.
  const int sc0 = ((kc ^ (arow & 7)) << 3);
  const int sc1 = (((4 + kc) ^ (arow & 7)) << 3);
  // region bases for reads
  const int rA0 = (0 * 2 + wm) * REG, rA1 = (1 * 2 + wm) * REG;
  const int rB0 = (0 * 2 + wnh) * REG, rB1 = (1 * 2 + wnh) * REG;
  const int aRow = arow * 64;                       // + mf*1024
  const int bRow = ((wn & 1) * 64 + arow) * 64;     // + nf*1024

  // stage addressing: thread t covers chunk (it*512 + t); r = it*64 + (t>>3);
  // src col-chunk = (t&7) ^ ((t>>3)&7) -> per-thread constant.
  const int r0t = (tid >> 3);
  const int sswz = ((tid & 7) ^ ((tid >> 3) & 7)) << 3;
  const unsigned short* sA = A + (size_t)r0t * K + sswz;
  const unsigned short* sB = B + (size_t)r0t * K + sswz;
  const size_t row64 = (size_t)64 * K;
  const size_t hK = (size_t)128 * K;
  const size_t dst0 = (size_t)wid * 512;  // shorts; lane*16B added by HW

  auto stg = [&](unsigned short* region, const unsigned short* sbase, size_t koff) {
    async16(region + dst0, sbase + koff);
    async16(region + 4096 + dst0, sbase + row64 + koff);
  };

  f32x4 acc[8][4];
#pragma unroll
  for (int m = 0; m < 8; ++m)
#pragma unroll
    for (int n = 0; n < 4; ++n) acc[m][n] = (f32x4){0.f, 0.f, 0.f, 0.f};

  // prologue: tile0 all 4 halves (A,B) + tile1 B halves
  stg(LB + 0 * REG, sB, 0);
  stg(LB + 1 * REG, sB, hK);
  stg(LA + 0 * REG, sA, 0);
  stg(LA + 1 * REG, sA, hK);
  stg(LB + 2 * REG, sB, 64);
  stg(LB + 3 * REG, sB, hK + 64);
  asm volatile("s_waitcnt vmcnt(4)" ::: "memory");
  asm volatile("s_barrier" ::: "memory");

  bf16x8 afr[4][2], bfr[4][2];

  for (int T = 0; T < nt; T += 2) {
    const size_t k1 = (size_t)(T + 1) * 64;
    const size_t k2 = (size_t)((T + 2 < nt) ? T + 2 : 0) * 64;
    const size_t k3 = (size_t)((T + 3 < nt) ? T + 3 : 0) * 64;

    // ---- p0 (tile T, db0): bfr nf0-1, afr mf0-3; stage A-db1-h0(T+1)
#pragma unroll
    for (int nf = 0; nf < 2; ++nf) {
      bfr[nf][0] = *(const bf16x8*)&LB[rB0 + bRow + nf * 1024 + sc0];
      bfr[nf][1] = *(const bf16x8*)&LB[rB0 + bRow + nf * 1024 + sc1];
    }
#pragma unroll
    for (int i = 0; i < 4; ++i) {
      afr[i][0] = *(const bf16x8*)&LA[rA0 + aRow + i * 1024 + sc0];
      afr[i][1] = *(const bf16x8*)&LA[rA0 + aRow + i * 1024 + sc1];
    }
    stg(LA + 2 * REG, sA, k1);
    __builtin_amdgcn_s_setprio(1);
#pragma unroll
    for (int i = 0; i < 4; ++i)
#pragma unroll
      for (int nf = 0; nf < 2; ++nf)
#pragma unroll
        for (int s = 0; s < 2; ++s)
          acc[i][nf] = __builtin_amdgcn_mfma_f32_16x16x32_bf16(afr[i][s], bfr[nf][s], acc[i][nf], 0, 0, 0);
    __builtin_amdgcn_s_setprio(0);
    asm volatile("s_barrier" ::: "memory");

    // ---- p1: bfr nf2-3; stage A-db1-h1(T+1)
#pragma unroll
    for (int nf = 2; nf < 4; ++nf) {
      bfr[nf][0] = *(const bf16x8*)&LB[rB0 + bRow + nf * 1024 + sc0];
      bfr[nf][1] = *(const bf16x8*)&LB[rB0 + bRow + nf * 1024 + sc1];
    }
    stg(LA + 3 * REG, sA, hK + k1);
    __builtin_amdgcn_s_setprio(1);
#pragma unroll
    for (int i = 0; i < 4; ++i)
#pragma unroll
      for (int nf = 2; nf < 4; ++nf)
#pragma unroll
        for (int s = 0; s < 2; ++s)
          acc[i][nf] = __builtin_amdgcn_mfma_f32_16x16x32_bf16(afr[i][s], bfr[nf][s], acc[i][nf], 0, 0, 0);
    __builtin_amdgcn_s_setprio(0);
    asm volatile("s_barrier" ::: "memory");

    // ---- p2: afr mf4-7; stage B-db0-h0(T+2)
#pragma unroll
    for (int i = 0; i < 4; ++i) {
      afr[i][0] = *(const bf16x8*)&LA[rA0 + aRow + (4 + i) * 1024 + sc0];
      afr[i][1] = *(const bf16x8*)&LA[rA0 + aRow + (4 + i) * 1024 + sc1];
    }
    stg(LB + 0 * REG, sB, k2);
    __builtin_amdgcn_s_setprio(1);
#pragma unroll
    for (int i = 0; i < 4; ++i)
#pragma unroll
      for (int nf = 2; nf < 4; ++nf)
#pragma unroll
        for (int s = 0; s < 2; ++s)
          acc[4 + i][nf] = __builtin_amdgcn_mfma_f32_16x16x32_bf16(afr[i][s], bfr[nf][s], acc[4 + i][nf], 0, 0, 0);
    __builtin_amdgcn_s_setprio(0);
    asm volatile("s_barrier" ::: "memory");

    // ---- p3: no reads (bfr nf0-1 live); stage B-db0-h1(T+2); vmcnt
    stg(LB + 1 * REG, sB, hK + k2);
    __builtin_amdgcn_s_setprio(1);
#pragma unroll
    for (int i = 0; i < 4; ++i)
#pragma unroll
      for (int nf = 0; nf < 2; ++nf)
#pragma unroll
        for (int s = 0; s < 2; ++s)
          acc[4 + i][nf] = __builtin_amdgcn_mfma_f32_16x16x32_bf16(afr[i][s], bfr[nf][s], acc[4 + i][nf], 0, 0, 0);
    __builtin_amdgcn_s_setprio(0);
    asm volatile("s_waitcnt vmcnt(4)" ::: "memory");
    asm volatile("s_barrier" ::: "memory");

    // ---- p4 (tile T+1, db1): bfr nf0-1, afr mf0-3; stage A-db0-h0(T+2)
#pragma unroll
    for (int nf = 0; nf < 2; ++nf) {
      bfr[nf][0] = *(const bf16x8*)&LB[rB1 + bRow + nf * 1024 + sc0];
      bfr[nf][1] = *(const bf16x8*)&LB[rB1 + bRow + nf * 1024 + sc1];
    }
#pragma unroll
    for (int i = 0; i < 4; ++i) {
      afr[i][0] = *(const bf16x8*)&LA[rA1 + aRow + i * 1024 + sc0];
      afr[i][1] = *(const bf16x8*)&LA[rA1 + aRow + i * 1024 + sc1];
    }
    stg(LA + 0 * REG, sA, k2);
    __builtin_amdgcn_s_setprio(1);
#pragma unroll
    for (int i = 0; i < 4; ++i)
#pragma unroll
      for (int nf = 0; nf < 2; ++nf)
#pragma unroll
        for (int s = 0; s < 2; ++s)
          acc[i][nf] = __builtin_amdgcn_mfma_f32_16x16x32_bf16(afr[i][s], bfr[nf][s], acc[i][nf], 0, 0, 0);
    __builtin_amdgcn_s_setprio(0);
    asm volatile("s_barrier" ::: "memory");

    // ---- p5: bfr nf2-3; stage A-db0-h1(T+2)
#pragma unroll
    for (int nf = 2; nf < 4; ++nf) {
      bfr[nf][0] = *(const bf16x8*)&LB[rB1 + bRow + nf * 1024 + sc0];
      bfr[nf][1] = *(const bf16x8*)&LB[rB1 + bRow + nf * 1024 + sc1];
    }
    stg(LA + 1 * REG, sA, hK + k2);
    __builtin_amdgcn_s_setprio(1);
#pragma unroll
    for (int i = 0; i < 4; ++i)
#pragma unroll
      for (int nf = 2; nf < 4; ++nf)
#pragma unroll
        for (int s = 0; s < 2; ++s)
          acc[i][nf] = __builtin_amdgcn_mfma_f32_16x16x32_bf16(afr[i][s], bfr[nf][s], acc[i][nf], 0, 0, 0);
    __builtin_amdgcn_s_setprio(0);
    asm volatile("s_barrier" ::: "memory");

    // ---- p6: afr mf4-7; stage B-db1-h0(T+3)
#pragma unroll
    for (int i = 0; i < 4; ++i) {
      afr[i][0] = *(const bf16x8*)&LA[rA1 + aRow + (4 + i) * 1024 + sc0];
      afr[i][1] = *(const bf16x8*)&LA[rA1 + aRow + (4 + i) * 1024 + sc1];
    }
    stg(LB + 2 * REG, sB, k3);
    __builtin_amdgcn_s_setprio(1);
#pragma unroll
    for (int i = 0; i < 4; ++i)
#pragma unroll
      for (int nf = 2; nf < 4; ++nf)
#pragma unroll
        for (int s = 0; s < 2; ++s)
          acc[4 + i][nf] = __builtin_amdgcn_mfma_f32_16x16x32_bf16(afr[i][s], bfr[nf][s], acc[4 + i][nf], 0, 0, 0);
    __builtin_amdgcn_s_setprio(0);
    asm volatile("s_barrier" ::: "memory");

    // ---- p7: no reads; stage B-db1-h1(T+3); vmcnt
    stg(LB + 3 * REG, sB, hK + k3);
    __builtin_amdgcn_s_setprio(1);
#pragma unroll
    for (int i = 0; i < 4; ++i)
#pragma unroll
      for (int nf = 0; nf < 2; ++nf)
#pragma unroll
        for (int s = 0; s < 2; ++s)
          acc[4 + i][nf] = __builtin_amdgcn_mfma_f32_16x16x32_bf16(afr[i][s], bfr[nf][s], acc[4 + i][nf], 0, 0, 0);
    __builtin_amdgcn_s_setprio(0);
    asm volatile("s_waitcnt vmcnt(4)" ::: "memory");
    asm volatile("s_barrier" ::: "memory");
  }
  asm volatile("s_waitcnt vmcnt(0)" ::: "memory");

  // epilogue: n innermost -> each 128B line completed back-to-back (no RMW).
  const int rl = (lane >> 4) * 4;
  const int cl = lane & 15;
  float bv[4];
#pragma unroll
  for (int n = 0; n < 4; ++n) {
    const int col = tn * 256 + wn * 64 + n * 16 + cl;
    bv[n] = bp ? bp[(size_t)e * Nn + col] : 0.f;
  }
#pragma unroll
  for (int m = 0; m < 8; ++m) {
    const int row = row0 + wm * 128 + m * 16 + rl;
#pragma unroll
    for (int jj = 0; jj < 4; ++jj) {
      CT* rowp = Cw + (size_t)(row + jj) * Nn + tn * 256 + wn * 64 + cl;
#pragma unroll
      for (int n = 0; n < 4; ++n) {
        float v = acc[m][n][jj] + bv[n];
        if (GELU) v = 0.5f * v * (1.f + erff(v * 0.70710678118654752f));
        if constexpr (sizeof(CT) == 2) { rowp[n * 16] = (CT)f2bf(v); } else { rowp[n * 16] = (CT)v; }
      }
    }
  }
}

// ---------------- combine: out[t] = g0*(Ya+Yb)[s0] + g1*(Ya+Yb)[s1] ----------------
__global__ __launch_bounds__(256) void combine_kernel(
    const float* __restrict__ Ya, const float* __restrict__ Yb,
    const int* __restrict__ tok_slot, const float* __restrict__ tok_g,
    float* __restrict__ out) {
  const int t = blockIdx.x;
  const int i = threadIdx.x;
  const int s0 = tok_slot[2 * t], s1 = tok_slot[2 * t + 1];
  const float g0 = tok_g[2 * t], g1 = tok_g[2 * t + 1];
  const float4 a0 = ((const float4*)Ya)[(size_t)s0 * 256 + i];
  const float4 b0 = ((const float4*)Yb)[(size_t)s0 * 256 + i];
  const float4 a1 = ((const float4*)Ya)[(size_t)s1 * 256 + i];
  const float4 b1 = ((const float4*)Yb)[(size_t)s1 * 256 + i];
  float4 r;
  r.x = g0 * (a0.x + b0.x) + g1 * (a1.x + b1.x);
  r.y = g0 * (a0.y + b0.y) + g1 * (a1.y + b1.y);
  r.z = g0 * (a0.z + b0.z) + g1 * (a1.z + b1.z);
  r.w = g0 * (a0.w + b0.w) + g1 * (a1.w + b1.w);
  ((float4*)out)[(size_t)t * 256 + i] = r;
}

extern "C" void kernel_launch(void* const* d_in, const int* in_sizes, int n_in,
                              void* d_out, int out_size, void* d_ws, size_t ws_size,
                              hipStream_t stream) {
  const float* x = (const float*)d_in[0];
  const float* Wr = (const float*)d_in[1];
  const float* W1 = (const float*)d_in[2];
  const float* b1 = (const float*)d_in[3];
  const float* W2 = (const float*)d_in[4];
  const float* b2 = (const float*)d_in[5];
  float* out = (float*)d_out;

  char* w = (char*)d_ws;
  size_t ob = 0;
  auto take = [&](size_t nbytes) -> void* {
    void* p = w + ob;
    ob = (ob + nbytes + 255) & ~(size_t)255;
    return p;
  };
  // Overlap: {W1T,Xg} (dead after GEMM1) share a region with {Ya,Yb}
  unsigned short* W2T = (unsigned short*)take((size_t)NE * DM * DFF * 2);   // 64MB
  unsigned short* H = (unsigned short*)take((size_t)CAP * DFF * 2);         // 151MB
  char* R = (char*)take(2 * (size_t)CAP * DM * 4);                          // 151MB
  unsigned short* W1T = (unsigned short*)R;                                 // 64MB
  unsigned short* Xg = (unsigned short*)(R + (size_t)NE * DFF * DM * 2);    // 37.75MB
  float* Ya = (float*)R;                                                    // 75.5MB
  float* Yb = (float*)(R + (size_t)CAP * DM * 4);                           // 75.5MB
  unsigned* counts = (unsigned*)take(NE * 4);
  float* Psum = (float*)take(NE * 4);
  int* offs = (int*)take(16 * 4);
  int* tok_e = (int*)take(2 * N_TOK * 4);
  float* tok_g = (float*)take(2 * N_TOK * 4);
  int* tok_ls = (int*)take(2 * N_TOK * 4);
  int* tok_slot = (int*)take(2 * N_TOK * 4);
  (void)ws_size; (void)in_sizes; (void)n_in; (void)out_size;

  hipFuncSetAttribute(reinterpret_cast<const void*>(&gemm8<1, true, unsigned short>),
                      hipFuncAttributeMaxDynamicSharedMemorySize, 131072);
  hipFuncSetAttribute(reinterpret_cast<const void*>(&gemm8<2, false, float>),
                      hipFuncAttributeMaxDynamicSharedMemorySize, 131072);

  init_kernel<<<1, 64, 0, stream>>>(counts, Psum);
  router_kernel<<<N_TOK / 16, 256, 0, stream>>>(x, Wr, counts, Psum, tok_e, tok_g, tok_ls);
  transpose_cvt<<<dim3(DFF / 64, DM / 64, NE), 256, 0, stream>>>(W1, W1T, DM, DFF);
  transpose_cvt<<<dim3(DM / 64, DFF / 64, NE), 256, 0, stream>>>(W2, W2T, DFF, DM);
  offsets_kernel<<<1, 64, 0, stream>>>(counts, Psum, offs, out + (size_t)N_TOK * DM);
  gather_kernel<<<N_TOK, 256, 0, stream>>>(x, tok_e, tok_ls, offs, tok_slot, Xg);
  // GEMM1: H = gelu(Xg @ W1 + b1); grid: x=tn (A-panel shared), y=global row-tile
  gemm8<1, true, unsigned short><<<dim3(DFF / 256, TMG, 1), 512, 131072, stream>>>(
      Xg, W1T, b1, H, offs, DM, DFF, 0);
  // GEMM2 split-K=2: z = half; halves write Ya / Yb
  gemm8<2, false, float><<<dim3(DM / 256, TMG, 2), 512, 131072, stream>>>(
      H, W2T, b2, Ya, offs, DFF, DM, (size_t)CAP * DM);
  combine_kernel<<<N_TOK, 256, 0, stream>>>(Ya, Yb, tok_slot, tok_g, out);
}